// Round 10
// baseline (890.780 us; speedup 1.0000x reference)
//
#include <hip/hip_runtime.h>
#include <hip/hip_bf16.h>

// ---------------------------------------------------------------------------
// QuadraticGNN: 3x ResGatedGraphConv (ReLU gate, LeakyReLU 0.01, linear Wl)
//               -> global mean pool (32 graphs) -> 5-layer MLP with BN.
// Round 22 (= R21 resubmit; R21 hit "container failed twice" with no
// kernel error — audit found no OOB/hang vector and R18->R19 precedent
// shows these failures include infra flakes):
//   - gemm2: NO LDS, NO barriers. Per K-step each wave loads 2 A-frags +
//     8 B-frags (contiguous short8) straight to registers, 16 MFMAs.
//     B is L2-resident (<=512KB); A rows are wave-private (LDS staging
//     de-duplicated nothing and its barriers were the measured stall).
//     Changes vs R21: plain __launch_bounds__(512) (no min-occ hint),
//     B offsets as size_t scalars. Both behavior-neutral.
//   - Everything else identical to the green R19/R20 builds.
// ---------------------------------------------------------------------------

#define GN_N 100000
#define GN_E 300000
#define GN_G 32

typedef __attribute__((ext_vector_type(8))) short short8;
typedef __attribute__((ext_vector_type(4))) float floatx4;

__device__ inline ushort f2bf_rne(float f) {
    unsigned u = __float_as_uint(f);
    unsigned r = u + 0x7fffu + ((u >> 16) & 1u);
    return (ushort)(r >> 16);
}
__device__ inline float bf2f(ushort h) { return __uint_as_float(((unsigned)h) << 16); }

// W-array layout (ushort offsets), k-major [col][K] per segment.
// L1: 256 cols x K128 [K64|QV128|S64].
// L2 (composed Wl1@Wg2): 512 cols x K64 [K128|QV256|S128].
// L3 (composed Wl2@Wg3): 2 groups x 512 cols x K128 [K128|QV256|S128].
#define WOFF_L2   32768
#define WOFF_L3   65536
#define W_TOTAL   196608

struct W1Src { const float* Wg[4]; const float* bg[4]; };
struct CSrc  { const float* Wl; const float* bl; const float* Wg[4]; const float* bg[4]; };

__global__ void wconv_l1(W1Src S, ushort* __restrict__ hi, ushort* __restrict__ lo,
                         float* __restrict__ biascat)
{
    int id = blockIdx.x * 256 + threadIdx.x;
    if (id < 32768) {
        int g  = id >> 13;          // 4 gates x (64 cols x 128 k)
        int r2 = id & 8191;
        int c  = r2 >> 7;
        int k  = r2 & 127;
        float v = S.Wg[g][k * 64 + c];
        int colIdx = (g == 0) ? c : (g == 3) ? (192 + c) : (64 + 2 * c + (g - 1));
        int dst = colIdx * 128 + k;
        ushort h = f2bf_rne(v);
        hi[dst] = h; lo[dst] = f2bf_rne(v - bf2f(h));
    } else if (id < 32768 + 256) {
        int p = id - 32768;
        int g, cc;
        if (p < 64)       { g = 0; cc = p; }
        else if (p < 192) { g = 1 + ((p - 64) & 1); cc = (p - 64) >> 1; }
        else              { g = 3; cc = p - 192; }
        biascat[p] = S.bg[g][cc];
    }
}

// W2' = Wl1(64x64) @ Wg2(64x128/gate): 512 packed cols x K=64.
__global__ void compose_l2(CSrc S, ushort* __restrict__ hi, ushort* __restrict__ lo,
                           float* __restrict__ biascat)
{
    int id = blockIdx.x * 256 + threadIdx.x;
    if (id >= 512 * 64) return;
    int p = id >> 6, k = id & 63;
    int g, cc;
    if (p < 128)      { g = 0; cc = p; }
    else if (p < 384) { g = 1 + ((p - 128) & 1); cc = (p - 128) >> 1; }
    else              { g = 3; cc = p - 384; }
    const float* wg = S.Wg[g];
    float acc = 0.f;
    #pragma unroll 8
    for (int j = 0; j < 64; ++j)
        acc += S.Wl[k * 64 + j] * wg[j * 128 + cc];
    int dst = WOFF_L2 + p * 64 + k;
    ushort h = f2bf_rne(acc);
    hi[dst] = h; lo[dst] = f2bf_rne(acc - bf2f(h));
    if (k == 0) {
        float b = S.bg[g][cc];
        #pragma unroll 8
        for (int j = 0; j < 64; ++j) b += S.bl[j] * wg[j * 128 + cc];
        biascat[256 + p] = b;
    }
}

// W3' = Wl2(128x128) @ Wg3(128x256/gate): 2 groups x 512 packed cols x K=128.
__global__ void compose_l3(CSrc S, ushort* __restrict__ hi, ushort* __restrict__ lo,
                           float* __restrict__ biascat)
{
    int id = blockIdx.x * 256 + threadIdx.x;
    if (id >= 1024 * 128) return;
    int p = id >> 7, k = id & 127;
    int ch = p >> 9, pp = p & 511;
    int g, cc;
    if (pp < 128)      { g = 0; cc = pp; }
    else if (pp < 384) { g = 1 + ((pp - 128) & 1); cc = (pp - 128) >> 1; }
    else               { g = 3; cc = pp - 384; }
    int srcc = ch * 128 + cc;
    const float* wg = S.Wg[g];
    float acc = 0.f;
    #pragma unroll 8
    for (int j = 0; j < 128; ++j)
        acc += S.Wl[k * 128 + j] * wg[j * 256 + srcc];
    int dst = WOFF_L3 + ch * 65536 + pp * 128 + k;
    ushort h = f2bf_rne(acc);
    hi[dst] = h; lo[dst] = f2bf_rne(acc - bf2f(h));
    if (k == 0) {
        float b = S.bg[g][srcc];
        #pragma unroll 8
        for (int j = 0; j < 128; ++j) b += S.bl[j] * wg[j * 256 + srcc];
        biascat[768 + ch * 512 + pp] = b;
    }
}

// x (fp32 [N][128]) -> bf16 [N][128]; also zeroes the striped pool sums.
__global__ void aconv(const float* __restrict__ A, ushort* __restrict__ O,
                      float* __restrict__ sums)
{
    int id = blockIdx.x * 256 + threadIdx.x;
    if (id < 32 * GN_G * 256) sums[id] = 0.0f;
    if (id >= GN_N * 16) return;
    int r = id >> 4, cc = id & 15;
    const float* src = A + (size_t)r * 128 + cc * 8;
    short8 h;
    #pragma unroll
    for (int j = 0; j < 8; ++j) h[j] = (short)f2bf_rne(src[j]);
    *(short8*)&O[(size_t)r * 128 + cc * 8] = h;
}

// GEMM: 128 rows x 128 cols per block, 512 threads / 8 waves.
// NO LDS, NO barriers: per K-step each wave loads 2 A-fragments + 8
// B-fragments (contiguous short8) straight to registers, 16 MFMAs.
// B is L2-resident (<=512KB); A rows are wave-private (no cross-wave
// reuse existed -> LDS was pure overhead). Grid (ncb, rb) col-fast.
__global__ __launch_bounds__(512) void gemm2(
    const ushort* __restrict__ Aptr, int lda,
    const ushort* __restrict__ Bh, const ushort* __restrict__ Bl,
    const float* __restrict__ bias,
    ushort* __restrict__ Obf, int ldo,
    int K)
{
    const int tid  = threadIdx.x;
    const int w    = tid >> 6, lane = tid & 63;
    const int m    = lane & 15, quad = lane >> 4;
    const int row0 = blockIdx.y * 128;
    const int col0 = blockIdx.x * 128;
    const int wr   = (w >> 1) * 32;
    const int wc   = (w & 1) * 64;

    floatx4 acc[2][4];
    #pragma unroll
    for (int i = 0; i < 2; ++i)
        #pragma unroll
        for (int j = 0; j < 4; ++j) acc[i][j] = (floatx4){0.f, 0.f, 0.f, 0.f};

    int r0 = row0 + wr + m;
    int r1 = r0 + 16;
    r0 = r0 < GN_N ? r0 : 0;      // clamp: in-bounds reads; outputs guarded
    r1 = r1 < GN_N ? r1 : 0;
    const ushort* aP0 = Aptr + (size_t)r0 * lda + quad * 8;
    const ushort* aP1 = Aptr + (size_t)r1 * lda + quad * 8;
    const size_t bOff = (size_t)(col0 + wc + m) * K + quad * 8;
    const size_t bStride16 = (size_t)16 * K;

    for (int k0 = 0; k0 < K; k0 += 32) {
        short8 a0 = *(const short8*)(aP0 + k0);
        short8 a1 = *(const short8*)(aP1 + k0);
        short8 bh[4], bl[4];
        #pragma unroll
        for (int ct = 0; ct < 4; ++ct) {
            bh[ct] = *(const short8*)(Bh + bOff + ct * bStride16 + k0);
            bl[ct] = *(const short8*)(Bl + bOff + ct * bStride16 + k0);
        }
        #pragma unroll
        for (int ct = 0; ct < 4; ++ct) {
            acc[0][ct] = __builtin_amdgcn_mfma_f32_16x16x32_bf16(a0, bh[ct], acc[0][ct], 0, 0, 0);
            acc[0][ct] = __builtin_amdgcn_mfma_f32_16x16x32_bf16(a0, bl[ct], acc[0][ct], 0, 0, 0);
            acc[1][ct] = __builtin_amdgcn_mfma_f32_16x16x32_bf16(a1, bh[ct], acc[1][ct], 0, 0, 0);
            acc[1][ct] = __builtin_amdgcn_mfma_f32_16x16x32_bf16(a1, bl[ct], acc[1][ct], 0, 0, 0);
        }
    }

    #pragma unroll
    for (int rt = 0; rt < 2; ++rt) {
        #pragma unroll
        for (int ct = 0; ct < 4; ++ct) {
            int ocol = col0 + wc + ct * 16 + m;
            float bb = bias[ocol];
            #pragma unroll
            for (int reg = 0; reg < 4; ++reg) {
                int orow = row0 + wr + rt * 16 + quad * 4 + reg;
                if (orow >= GN_N) continue;
                Obf[(size_t)orow * ldo + ocol] = f2bf_rne(acc[rt][ct][reg] + bb);
            }
        }
    }
}

// ---------------- CSR build ----------------
__global__ void zero_int(int* p, int n)
{
    int i = blockIdx.x * 256 + threadIdx.x;
    if (i < n) p[i] = 0;
}

__global__ void hist_kernel(const int* __restrict__ dst, int* __restrict__ deg)
{
    int e = blockIdx.x * 256 + threadIdx.x;
    if (e < GN_E) atomicAdd(&deg[dst[e]], 1);
}

__global__ void scan1(const int* __restrict__ deg, int* __restrict__ rp, int* __restrict__ bsums)
{
    __shared__ int s[256];
    int b = blockIdx.x, t = threadIdx.x;
    int i = b * 256 + t;
    int v = (i < GN_N) ? deg[i] : 0;
    s[t] = v;
    __syncthreads();
    for (int off = 1; off < 256; off <<= 1) {
        int x = (t >= off) ? s[t - off] : 0;
        __syncthreads();
        s[t] += x;
        __syncthreads();
    }
    if (i < GN_N) rp[i] = s[t] - v;
    if (t == 255) bsums[b] = s[255];
}

__global__ __launch_bounds__(512) void scan2(int* bsums, int nb)
{
    __shared__ int s[512];
    int t = threadIdx.x;
    int v = (t < nb) ? bsums[t] : 0;
    s[t] = v;
    __syncthreads();
    for (int off = 1; off < 512; off <<= 1) {
        int x = (t >= off) ? s[t - off] : 0;
        __syncthreads();
        s[t] += x;
        __syncthreads();
    }
    if (t < nb) bsums[t] = s[t] - v;
}

__global__ void scan3(const int* __restrict__ bsums, int* __restrict__ rp, int* __restrict__ cursor)
{
    int b = blockIdx.x, t = threadIdx.x;
    int i = b * 256 + t;
    if (i < GN_N) {
        int v = rp[i] + bsums[b];
        rp[i] = v; cursor[i] = v;
    }
    if (i == 0) rp[GN_N] = GN_E;
}

__global__ void scatter_kernel(
    const int* __restrict__ src, const int* __restrict__ dst,
    int* __restrict__ cursor, int* __restrict__ elist)
{
    int e = blockIdx.x * 256 + threadIdx.x;
    if (e >= GN_E) return;
    int d = dst[e];
    int pos = atomicAdd(&cursor[d], 1);
    elist[pos] = src[e];
}

__global__ void bounds_kernel(const int* __restrict__ batch, int* __restrict__ se)
{
    int i = blockIdx.x * 256 + threadIdx.x;
    if (i >= GN_N) return;
    int g = batch[i];
    if (i == 0 || batch[i - 1] != g) se[g] = i;
    if (i == GN_N - 1 || batch[i + 1] != g) se[32 + g] = i + 1;
}

__global__ void cnt_kernel(const int* __restrict__ se, float* __restrict__ cnt)
{
    int g = threadIdx.x;
    if (g < GN_G) cnt[g] = (float)(se[32 + g] - se[g]);
}

// Layer-1 gather. Gbf row 256 = [K64|QV128|S64]. 4 nodes/wave, 8-edge batch.
// Writes leaky(h1_pre) bf16 [N][64].
__global__ __launch_bounds__(256, 2) void edge_gather_w(
    const ushort* __restrict__ Gbf, ushort* __restrict__ Abf,
    const int* __restrict__ row_ptr, const int* __restrict__ elist)
{
    int w = threadIdx.x >> 6, c = threadIdx.x & 63;
    int n0 = blockIdx.x * 16 + w * 4;

    float k[4], acc[4];
    int beg[4], end[4];
    #pragma unroll
    for (int j = 0; j < 4; ++j) {
        int node = n0 + j;
        bool ok = node < GN_N;
        int nd = ok ? node : 0;
        beg[j] = row_ptr[nd];
        end[j] = ok ? row_ptr[nd + 1] : beg[j];
        k[j]   = bf2f(Gbf[(size_t)nd * 256 + c]);
        acc[j] = bf2f(Gbf[(size_t)nd * 256 + 192 + c]);
    }
    int s[32];
    #pragma unroll
    for (int j = 0; j < 4; ++j) {
        #pragma unroll
        for (int e = 0; e < 8; ++e) {
            int idx = beg[j] + e;
            s[j * 8 + e] = elist[idx < end[j] ? idx : 0];
        }
    }
    uint qv[32];
    #pragma unroll
    for (int je = 0; je < 32; ++je)
        qv[je] = *(const uint*)&Gbf[(size_t)s[je] * 256 + 64 + 2 * c];
    #pragma unroll
    for (int j = 0; j < 4; ++j) {
        #pragma unroll
        for (int e = 0; e < 8; ++e) {
            if (beg[j] + e < end[j]) {
                uint p = qv[j * 8 + e];
                float gt = k[j] + bf2f((ushort)(p & 0xffffu));
                if (gt > 0.f) acc[j] += gt * bf2f((ushort)(p >> 16));
            }
        }
    }
    #pragma unroll
    for (int j = 0; j < 4; ++j) {
        for (int i = beg[j] + 8; i < end[j]; ++i) {
            int ss = elist[i];
            uint p = *(const uint*)&Gbf[(size_t)ss * 256 + 64 + 2 * c];
            float gt = k[j] + bf2f((ushort)(p & 0xffffu));
            if (gt > 0.f) acc[j] += gt * bf2f((ushort)(p >> 16));
        }
    }
    #pragma unroll
    for (int j = 0; j < 4; ++j)
        if (n0 + j < GN_N) {
            float a = acc[j];
            a = a > 0.f ? a : 0.01f * a;   // leaky here (fp32) -> gemm is pure copy
            Abf[(size_t)(n0 + j) * 64 + c] = f2bf_rne(a);
        }
}

// Layer-2 dual gather. Gbf row 512 = [K128|QV256|S128]; thread handles
// channels c and 64+c. Writes leaky(h2_pre) bf16 [N][128].
__global__ __launch_bounds__(256, 2) void edge_gather_w2(
    const ushort* __restrict__ Gbf, ushort* __restrict__ Abf,
    const int* __restrict__ row_ptr, const int* __restrict__ elist)
{
    int w = threadIdx.x >> 6, c = threadIdx.x & 63;
    int n0 = blockIdx.x * 16 + w * 4;

    float k0[4], k1[4], a0[4], a1[4];
    int beg[4], end[4];
    #pragma unroll
    for (int j = 0; j < 4; ++j) {
        int node = n0 + j;
        bool ok = node < GN_N;
        int nd = ok ? node : 0;
        beg[j] = row_ptr[nd];
        end[j] = ok ? row_ptr[nd + 1] : beg[j];
        size_t b = (size_t)nd * 512;
        k0[j] = bf2f(Gbf[b + c]);
        k1[j] = bf2f(Gbf[b + 64 + c]);
        a0[j] = bf2f(Gbf[b + 384 + c]);
        a1[j] = bf2f(Gbf[b + 448 + c]);
    }
    int s[32];
    #pragma unroll
    for (int j = 0; j < 4; ++j) {
        #pragma unroll
        for (int e = 0; e < 8; ++e) {
            int idx = beg[j] + e;
            s[j * 8 + e] = elist[idx < end[j] ? idx : 0];
        }
    }
    uint qv0[32], qv1[32];
    #pragma unroll
    for (int je = 0; je < 32; ++je) {
        size_t b = (size_t)s[je] * 512;
        qv0[je] = *(const uint*)&Gbf[b + 128 + 2 * c];
        qv1[je] = *(const uint*)&Gbf[b + 256 + 2 * c];
    }
    #pragma unroll
    for (int j = 0; j < 4; ++j) {
        #pragma unroll
        for (int e = 0; e < 8; ++e) {
            if (beg[j] + e < end[j]) {
                uint p = qv0[j * 8 + e];
                float gt = k0[j] + bf2f((ushort)(p & 0xffffu));
                if (gt > 0.f) a0[j] += gt * bf2f((ushort)(p >> 16));
                uint q = qv1[j * 8 + e];
                float gu = k1[j] + bf2f((ushort)(q & 0xffffu));
                if (gu > 0.f) a1[j] += gu * bf2f((ushort)(q >> 16));
            }
        }
    }
    #pragma unroll
    for (int j = 0; j < 4; ++j) {
        for (int i = beg[j] + 8; i < end[j]; ++i) {
            size_t b = (size_t)elist[i] * 512;
            uint p = *(const uint*)&Gbf[b + 128 + 2 * c];
            uint q = *(const uint*)&Gbf[b + 256 + 2 * c];
            float gt = k0[j] + bf2f((ushort)(p & 0xffffu));
            if (gt > 0.f) a0[j] += gt * bf2f((ushort)(p >> 16));
            float gu = k1[j] + bf2f((ushort)(q & 0xffffu));
            if (gu > 0.f) a1[j] += gu * bf2f((ushort)(q >> 16));
        }
    }
    #pragma unroll
    for (int j = 0; j < 4; ++j)
        if (n0 + j < GN_N) {
            float x = a0[j], y = a1[j];
            x = x > 0.f ? x : 0.01f * x;
            y = y > 0.f ? y : 0.01f * y;
            Abf[(size_t)(n0 + j) * 128 + c]      = f2bf_rne(x);
            Abf[(size_t)(n0 + j) * 128 + 64 + c] = f2bf_rne(y);
        }
}

// Layer-3 dual gather + leaky + pool. Gbf row 512; channels c0+c, c0+64+c.
__global__ __launch_bounds__(256, 2) void edge_gather_pool2(
    const ushort* __restrict__ Gbf,
    const int* __restrict__ row_ptr, const int* __restrict__ elist,
    const int* __restrict__ batch,
    float* __restrict__ sums, int c0)
{
    __shared__ float red[16][128];
    __shared__ int gid[16];
    int w = threadIdx.x >> 6, c = threadIdx.x & 63;
    int n0 = blockIdx.x * 16 + w * 4;

    float k0[4], k1[4], a0[4], a1[4];
    int beg[4], end[4];
    #pragma unroll
    for (int j = 0; j < 4; ++j) {
        int node = n0 + j;
        bool ok = node < GN_N;
        int nd = ok ? node : 0;
        beg[j] = row_ptr[nd];
        end[j] = ok ? row_ptr[nd + 1] : beg[j];
        size_t b = (size_t)nd * 512;
        k0[j] = bf2f(Gbf[b + c]);
        k1[j] = bf2f(Gbf[b + 64 + c]);
        a0[j] = ok ? bf2f(Gbf[b + 384 + c]) : 0.f;
        a1[j] = ok ? bf2f(Gbf[b + 448 + c]) : 0.f;
    }
    int s[32];
    #pragma unroll
    for (int j = 0; j < 4; ++j) {
        #pragma unroll
        for (int e = 0; e < 8; ++e) {
            int idx = beg[j] + e;
            s[j * 8 + e] = elist[idx < end[j] ? idx : 0];
        }
    }
    uint qv0[32], qv1[32];
    #pragma unroll
    for (int je = 0; je < 32; ++je) {
        size_t b = (size_t)s[je] * 512;
        qv0[je] = *(const uint*)&Gbf[b + 128 + 2 * c];
        qv1[je] = *(const uint*)&Gbf[b + 256 + 2 * c];
    }
    #pragma unroll
    for (int j = 0; j < 4; ++j) {
        #pragma unroll
        for (int e = 0; e < 8; ++e) {
            if (beg[j] + e < end[j]) {
                uint p = qv0[j * 8 + e];
                float gt = k0[j] + bf2f((ushort)(p & 0xffffu));
                if (gt > 0.f) a0[j] += gt * bf2f((ushort)(p >> 16));
                uint q = qv1[j * 8 + e];
                float gu = k1[j] + bf2f((ushort)(q & 0xffffu));
                if (gu > 0.f) a1[j] += gu * bf2f((ushort)(q >> 16));
            }
        }
    }
    #pragma unroll
    for (int j = 0; j < 4; ++j) {
        for (int i = beg[j] + 8; i < end[j]; ++i) {
            size_t b = (size_t)elist[i] * 512;
            uint p = *(const uint*)&Gbf[b + 128 + 2 * c];
            uint q = *(const uint*)&Gbf[b + 256 + 2 * c];
            float gt = k0[j] + bf2f((ushort)(p & 0xffffu));
            if (gt > 0.f) a0[j] += gt * bf2f((ushort)(p >> 16));
            float gu = k1[j] + bf2f((ushort)(q & 0xffffu));
            if (gu > 0.f) a1[j] += gu * bf2f((ushort)(q >> 16));
        }
    }
    #pragma unroll
    for (int j = 0; j < 4; ++j) {
        float x = a0[j], y = a1[j];
        red[w * 4 + j][c]      = x > 0.f ? x : 0.01f * x;
        red[w * 4 + j][64 + c] = y > 0.f ? y : 0.01f * y;
    }
    if (c < 4) {
        int node = n0 + c;
        gid[w * 4 + c] = (node < GN_N) ? batch[node] : -1;
    }
    __syncthreads();
    if (w == 0) {
        int stripe = blockIdx.x & 31;
        int i = 0;
        while (i < 16) {
            int gg = gid[i];
            float s0 = 0.f, s1 = 0.f;
            int j = i;
            while (j < 16 && gid[j] == gg) { s0 += red[j][c]; s1 += red[j][64 + c]; ++j; }
            if (gg >= 0) {
                float* dstp = &sums[(size_t)(stripe * GN_G + gg) * 256 + c0 + c];
                atomicAdd(dstp, s0);
                atomicAdd(dstp + 64, s1);
            }
            i = j;
        }
    }
}

// One block per graph: reduce 32 stripes; Pl = sums[g]/cnt[g];
// Pg = Pl @ Wl3 + bl3; BN-MLP chain.
__global__ __launch_bounds__(256) void mlp_kernel(
    const float* __restrict__ sums, const float* __restrict__ cnt,
    const float* __restrict__ Wl3, const float* __restrict__ bl3,
    const float* __restrict__ W1, const float* __restrict__ b1,
    const float* __restrict__ Wh, const float* __restrict__ bh,
    const float* __restrict__ Wo, const float* __restrict__ bo,
    const float* __restrict__ gamma, const float* __restrict__ beta,
    const float* __restrict__ mean, const float* __restrict__ var,
    float* __restrict__ out)
{
    __shared__ float sp[256];
    __shared__ float pg[256];
    __shared__ float h0[64], h1[64];
    const int g = blockIdx.x;
    const int t = threadIdx.x;
    const float inv = 1.0f / fmaxf(cnt[g], 1.0f);

    {
        float acc = 0.f;
        #pragma unroll 8
        for (int st = 0; st < 32; ++st)
            acc += sums[(size_t)(st * GN_G + g) * 256 + t];
        sp[t] = acc * inv;
    }
    __syncthreads();

    {
        float a0 = 0.f, a1 = 0.f, a2 = 0.f, a3 = 0.f;
        #pragma unroll 4
        for (int k = 0; k < 256; k += 4) {
            a0 += sp[k + 0] * Wl3[(k + 0) * 256 + t];
            a1 += sp[k + 1] * Wl3[(k + 1) * 256 + t];
            a2 += sp[k + 2] * Wl3[(k + 2) * 256 + t];
            a3 += sp[k + 3] * Wl3[(k + 3) * 256 + t];
        }
        pg[t] = bl3[t] + ((a0 + a1) + (a2 + a3));
    }
    __syncthreads();

    if (t < 64) {
        float a0 = 0.f, a1 = 0.f, a2 = 0.f, a3 = 0.f;
        #pragma unroll 4
        for (int k = 0; k < 256; k += 4) {
            a0 += pg[k + 0] * W1[(k + 0) * 64 + t];
            a1 += pg[k + 1] * W1[(k + 1) * 64 + t];
            a2 += pg[k + 2] * W1[(k + 2) * 64 + t];
            a3 += pg[k + 3] * W1[(k + 3) * 64 + t];
        }
        float acc = b1[t] + ((a0 + a1) + (a2 + a3));
        float sc = gamma[t] * rsqrtf(var[t] + 1e-5f);
        acc = (acc - mean[t]) * sc + beta[t];
        h0[t] = fmaxf(acc, 0.0f);
    }
    __syncthreads();

    for (int L = 0; L < 3; ++L) {
        const float* W  = Wh + L * 64 * 64;
        const float* hin  = (L & 1) ? h1 : h0;
        float*       hout = (L & 1) ? h0 : h1;
        if (t < 64) {
            const float* ga = gamma + (L + 1) * 64;
            const float* be = beta  + (L + 1) * 64;
            const float* me = mean  + (L + 1) * 64;
            const float* va = var   + (L + 1) * 64;
            float a0 = 0.f, a1 = 0.f, a2 = 0.f, a3 = 0.f;
            #pragma unroll 4
            for (int k = 0; k < 64; k += 4) {
                a0 += hin[k + 0] * W[(k + 0) * 64 + t];
                a1 += hin[k + 1] * W[(k + 1) * 64 + t];
                a2 += hin[k + 2] * W[(k + 2) * 64 + t];
                a3 += hin[k + 3] * W[(k + 3) * 64 + t];
            }
            float acc = (bh + L * 64)[t] + ((a0 + a1) + (a2 + a3));
            float sc = ga[t] * rsqrtf(va[t] + 1e-5f);
            acc = (acc - me[t]) * sc + be[t];
            hout[t] = fmaxf(acc, 0.0f);
        }
        __syncthreads();
    }

    if (t < 8) {
        const float* hf = h1;
        float acc = bo[t];
        for (int k = 0; k < 64; ++k) acc += hf[k] * Wo[k * 8 + t];
        out[g * 8 + t] = acc;
    }
}

extern "C" void kernel_launch(void* const* d_in, const int* in_sizes, int n_in,
                              void* d_out, int out_size, void* d_ws, size_t ws_size,
                              hipStream_t stream)
{
    const int N = GN_N, E = GN_E;
    const float* x          = (const float*)d_in[0];
    const int*   edge_index = (const int*)d_in[1];
    const int*   batch      = (const int*)d_in[2];
    const int*   src = edge_index;
    const int*   dst = edge_index + E;
    auto F = [&](int i) { return (const float*)d_in[i]; };

    // ---- workspace layout ----
    float* ws    = (float*)d_ws;
    float* sums  = ws;                          // 32 stripes x 32 x 256
    float* cnt   = sums + 32 * GN_G * 256;      // 32
    float* bcat  = cnt + GN_G;                  // 1792
    ushort* Whi  = (ushort*)(bcat + 1792);
    ushort* Wlo  = Whi + W_TOTAL;
    ushort* xbf  = Wlo + W_TOTAL;               // N x 128 bf16
    ushort* h1bf = xbf + (size_t)N * 128;       // N x 64 bf16 (leaky'd)
    ushort* h2bf = h1bf + (size_t)N * 64;       // N x 128 bf16 (leaky'd)
    ushort* Gbf  = h2bf + (size_t)N * 128;      // N x 512 bf16
    int* deg     = (int*)(Gbf + (size_t)N * 512);
    int* cursor  = deg + N;
    int* row_ptr = cursor + N;                  // N+1
    int* elist   = row_ptr + (N + 1);           // E
    int* bsums   = elist + E;                   // 512
    int* se      = bsums + 512;                 // 64

    size_t need = (size_t)((char*)(se + 64) - (char*)ws);
    if (ws_size < need) return;

    // ---- CSR build + graph bounds ----
    const int eb = (E + 255) / 256;
    const int nb = (N + 255) / 256;
    zero_int<<<nb, 256, 0, stream>>>(deg, N);
    zero_int<<<1, 256, 0, stream>>>(se, 64);
    hist_kernel<<<eb, 256, 0, stream>>>(dst, deg);
    scan1<<<nb, 256, 0, stream>>>(deg, row_ptr, bsums);
    scan2<<<1, 512, 0, stream>>>(bsums, nb);
    scan3<<<nb, 256, 0, stream>>>(bsums, row_ptr, cursor);
    scatter_kernel<<<eb, 256, 0, stream>>>(src, dst, cursor, elist);
    bounds_kernel<<<nb, 256, 0, stream>>>(batch, se);
    cnt_kernel<<<1, 64, 0, stream>>>(se, cnt);

    // ---- weight prep: L1 pack; L2/L3 composed with previous Wl ----
    W1Src S1;
    for (int g = 0; g < 4; ++g) { S1.Wg[g] = F(3 + g); S1.bg[g] = F(7 + g); }
    wconv_l1<<<(32768 + 256 + 255) / 256, 256, 0, stream>>>(S1, Whi, Wlo, bcat);

    CSrc S2;
    S2.Wl = F(11); S2.bl = F(12);
    for (int g = 0; g < 4; ++g) { S2.Wg[g] = F(13 + g); S2.bg[g] = F(17 + g); }
    compose_l2<<<(512 * 64 + 255) / 256, 256, 0, stream>>>(S2, Whi, Wlo, bcat);

    CSrc S3;
    S3.Wl = F(21); S3.bl = F(22);
    for (int g = 0; g < 4; ++g) { S3.Wg[g] = F(23 + g); S3.bg[g] = F(27 + g); }
    compose_l3<<<(1024 * 128 + 255) / 256, 256, 0, stream>>>(S3, Whi, Wlo, bcat);

    aconv<<<(N * 16 + 255) / 256, 256, 0, stream>>>(x, xbf, sums);

    const int rb = (N + 127) / 128;
    const int gatherBlocks = (N + 15) / 16;

    // ---- layer 1 (256 cols: [K64|QV128|S64]) ----
    gemm2<<<dim3(2, rb), 512, 0, stream>>>(
        xbf, 128, Whi, Wlo, bcat, Gbf, 256, 128);
    edge_gather_w<<<gatherBlocks, 256, 0, stream>>>(Gbf, h1bf, row_ptr, elist);

    // ---- layer 2 (composed: leaky'd h1 @ Wl1Wg2; 512 cols, K=64) ----
    gemm2<<<dim3(4, rb), 512, 0, stream>>>(
        h1bf, 64, Whi + WOFF_L2, Wlo + WOFF_L2, bcat + 256, Gbf, 512, 64);
    edge_gather_w2<<<gatherBlocks, 256, 0, stream>>>(Gbf, h2bf, row_ptr, elist);

    // ---- layer 3 (composed: leaky'd h2 @ Wl2Wg3; 2 groups x 512, K=128) ----
    for (int ch = 0; ch < 2; ++ch) {
        size_t go = WOFF_L3 + (size_t)ch * 65536;
        gemm2<<<dim3(4, rb), 512, 0, stream>>>(
            h2bf, 128, Whi + go, Wlo + go, bcat + 768 + ch * 512, Gbf, 512, 128);
        edge_gather_pool2<<<gatherBlocks, 256, 0, stream>>>(
            Gbf, row_ptr, elist, batch, sums, ch * 128);
    }

    mlp_kernel<<<GN_G, 256, 0, stream>>>(sums, cnt, F(31), F(32),
                                         F(33), F(34), F(35), F(36), F(37), F(38),
                                         F(39), F(40), F(41), F(42),
                                         (float*)d_out);
}

// Round 11
// 637.475 us; speedup vs baseline: 1.3974x; 1.3974x over previous
//
#include <hip/hip_runtime.h>
#include <hip/hip_bf16.h>

// ---------------------------------------------------------------------------
// QuadraticGNN: 3x ResGatedGraphConv (ReLU gate, LeakyReLU 0.01, linear Wl)
//               -> global mean pool (32 graphs) -> 5-layer MLP with BN.
// Round 23 (revert + trim):
//   - R21/R22 no-LDS gemm regressed 2.3x (VGPR=40 -> allocator serialized
//     the 10 loads/K-step; WRITE amplified 101->140MB from L2 thrash).
//     Third failed attempt at beating the R19 gemm -> abandon the family.
//   - gemm2 restored to the EXACT R19 green body: global_load_lds(16B),
//     linear LDS double-buffer, pre-swizzled per-lane source addrs
//     (kc^((sub>>1)&3)), read-side same XOR (0 bank conflicts measured),
//     one __syncthreads per K-step, grid(ncb, rb) col-fast, 65.5us/gemm.
//   - cnt_kernel folded into mlp_kernel (counts from se directly): one
//     fewer dispatch.
// ---------------------------------------------------------------------------

#define GN_N 100000
#define GN_E 300000
#define GN_G 32

typedef __attribute__((ext_vector_type(8))) short short8;
typedef __attribute__((ext_vector_type(4))) float floatx4;

__device__ inline ushort f2bf_rne(float f) {
    unsigned u = __float_as_uint(f);
    unsigned r = u + 0x7fffu + ((u >> 16) & 1u);
    return (ushort)(r >> 16);
}
__device__ inline float bf2f(ushort h) { return __uint_as_float(((unsigned)h) << 16); }

// W-array layout (ushort offsets), k-major [col][K] per segment.
// L1: 256 cols x K128 [K64|QV128|S64].
// L2 (composed Wl1@Wg2): 512 cols x K64 [K128|QV256|S128].
// L3 (composed Wl2@Wg3): 2 groups x 512 cols x K128 [K128|QV256|S128].
#define WOFF_L2   32768
#define WOFF_L3   65536
#define W_TOTAL   196608

struct W1Src { const float* Wg[4]; const float* bg[4]; };
struct CSrc  { const float* Wl; const float* bl; const float* Wg[4]; const float* bg[4]; };

__global__ void wconv_l1(W1Src S, ushort* __restrict__ hi, ushort* __restrict__ lo,
                         float* __restrict__ biascat)
{
    int id = blockIdx.x * 256 + threadIdx.x;
    if (id < 32768) {
        int g  = id >> 13;          // 4 gates x (64 cols x 128 k)
        int r2 = id & 8191;
        int c  = r2 >> 7;
        int k  = r2 & 127;
        float v = S.Wg[g][k * 64 + c];
        int colIdx = (g == 0) ? c : (g == 3) ? (192 + c) : (64 + 2 * c + (g - 1));
        int dst = colIdx * 128 + k;
        ushort h = f2bf_rne(v);
        hi[dst] = h; lo[dst] = f2bf_rne(v - bf2f(h));
    } else if (id < 32768 + 256) {
        int p = id - 32768;
        int g, cc;
        if (p < 64)       { g = 0; cc = p; }
        else if (p < 192) { g = 1 + ((p - 64) & 1); cc = (p - 64) >> 1; }
        else              { g = 3; cc = p - 192; }
        biascat[p] = S.bg[g][cc];
    }
}

// W2' = Wl1(64x64) @ Wg2(64x128/gate): 512 packed cols x K=64.
__global__ void compose_l2(CSrc S, ushort* __restrict__ hi, ushort* __restrict__ lo,
                           float* __restrict__ biascat)
{
    int id = blockIdx.x * 256 + threadIdx.x;
    if (id >= 512 * 64) return;
    int p = id >> 6, k = id & 63;
    int g, cc;
    if (p < 128)      { g = 0; cc = p; }
    else if (p < 384) { g = 1 + ((p - 128) & 1); cc = (p - 128) >> 1; }
    else              { g = 3; cc = p - 384; }
    const float* wg = S.Wg[g];
    float acc = 0.f;
    #pragma unroll 8
    for (int j = 0; j < 64; ++j)
        acc += S.Wl[k * 64 + j] * wg[j * 128 + cc];
    int dst = WOFF_L2 + p * 64 + k;
    ushort h = f2bf_rne(acc);
    hi[dst] = h; lo[dst] = f2bf_rne(acc - bf2f(h));
    if (k == 0) {
        float b = S.bg[g][cc];
        #pragma unroll 8
        for (int j = 0; j < 64; ++j) b += S.bl[j] * wg[j * 128 + cc];
        biascat[256 + p] = b;
    }
}

// W3' = Wl2(128x128) @ Wg3(128x256/gate): 2 groups x 512 packed cols x K=128.
__global__ void compose_l3(CSrc S, ushort* __restrict__ hi, ushort* __restrict__ lo,
                           float* __restrict__ biascat)
{
    int id = blockIdx.x * 256 + threadIdx.x;
    if (id >= 1024 * 128) return;
    int p = id >> 7, k = id & 127;
    int ch = p >> 9, pp = p & 511;
    int g, cc;
    if (pp < 128)      { g = 0; cc = pp; }
    else if (pp < 384) { g = 1 + ((pp - 128) & 1); cc = (pp - 128) >> 1; }
    else               { g = 3; cc = pp - 384; }
    int srcc = ch * 128 + cc;
    const float* wg = S.Wg[g];
    float acc = 0.f;
    #pragma unroll 8
    for (int j = 0; j < 128; ++j)
        acc += S.Wl[k * 128 + j] * wg[j * 256 + srcc];
    int dst = WOFF_L3 + ch * 65536 + pp * 128 + k;
    ushort h = f2bf_rne(acc);
    hi[dst] = h; lo[dst] = f2bf_rne(acc - bf2f(h));
    if (k == 0) {
        float b = S.bg[g][srcc];
        #pragma unroll 8
        for (int j = 0; j < 128; ++j) b += S.bl[j] * wg[j * 256 + srcc];
        biascat[768 + ch * 512 + pp] = b;
    }
}

// x (fp32 [N][128]) -> bf16 [N][128]; also zeroes the striped pool sums.
__global__ void aconv(const float* __restrict__ A, ushort* __restrict__ O,
                      float* __restrict__ sums)
{
    int id = blockIdx.x * 256 + threadIdx.x;
    if (id < 32 * GN_G * 256) sums[id] = 0.0f;
    if (id >= GN_N * 16) return;
    int r = id >> 4, cc = id & 15;
    const float* src = A + (size_t)r * 128 + cc * 8;
    short8 h;
    #pragma unroll
    for (int j = 0; j < 8; ++j) h[j] = (short)f2bf_rne(src[j]);
    *(short8*)&O[(size_t)r * 128 + cc * 8] = h;
}

// GEMM: 128 rows x 128 cols per block, 512 threads / 8 waves, pure-copy A.
// global_load_lds(16B) staging into linear LDS double-buffer; per-lane
// source addresses pre-swizzled so reads (same XOR) are bank-balanced.
// Grid (ncb, rb): col-fast dispatch so co-resident blocks share A.
__global__ __launch_bounds__(512) void gemm2(
    const ushort* __restrict__ Aptr, int lda,
    const ushort* __restrict__ Bh, const ushort* __restrict__ Bl,
    const float* __restrict__ bias,
    ushort* __restrict__ Obf, int ldo,
    int K)
{
    __shared__ ushort sA[2][128 * 32];
    __shared__ ushort sBh[2][128 * 32], sBl[2][128 * 32];

    const int tid  = threadIdx.x;
    const int w    = tid >> 6, lane = tid & 63;
    const int m    = lane & 15, quad = lane >> 4;
    const int row0 = blockIdx.y * 128;
    const int col0 = blockIdx.x * 128;
    const int wr   = (w >> 1) * 32;
    const int wc   = (w & 1) * 64;

    // staging: wave w covers rows/cols w*16..w*16+15; lane -> (sub, kc).
    // LDS unit u = (w*16+sub)*4 + kc holds data chunk kc^((sub>>1)&3).
    const int sub = lane >> 2;
    const int kc  = lane & 3;
    const int kcs = kc ^ ((sub >> 1) & 3);
    const int arow = row0 + w * 16 + sub;
    const int arowc = arow < GN_N ? arow : 0;   // clamp: in-bounds DMA source
    const ushort* aSrc  = Aptr + (size_t)arowc * lda + kcs * 8;
    const ushort* bhSrc = Bh   + (size_t)(col0 + w * 16 + sub) * K + kcs * 8;
    const ushort* blSrc = Bl   + (size_t)(col0 + w * 16 + sub) * K + kcs * 8;

    floatx4 acc[2][4];
    #pragma unroll
    for (int i = 0; i < 2; ++i)
        #pragma unroll
        for (int j = 0; j < 4; ++j) acc[i][j] = (floatx4){0.f, 0.f, 0.f, 0.f};

    auto stage = [&](int buf, int k0) {
        __builtin_amdgcn_global_load_lds(
            (const __attribute__((address_space(1))) void*)(aSrc + k0),
            (__attribute__((address_space(3))) void*)&sA[buf][w * 512], 16, 0, 0);
        __builtin_amdgcn_global_load_lds(
            (const __attribute__((address_space(1))) void*)(bhSrc + k0),
            (__attribute__((address_space(3))) void*)&sBh[buf][w * 512], 16, 0, 0);
        __builtin_amdgcn_global_load_lds(
            (const __attribute__((address_space(1))) void*)(blSrc + k0),
            (__attribute__((address_space(3))) void*)&sBl[buf][w * 512], 16, 0, 0);
    };

    const int nt = K >> 5;
    stage(0, 0);
    __syncthreads();

    const int rsw = (quad ^ ((m >> 1) & 3)) * 8;   // read-side swizzle (ushorts)
    int cur = 0;
    for (int t = 0; t < nt; ++t) {
        if (t + 1 < nt) stage(cur ^ 1, (t + 1) << 5);
        short8 bhf[4], blf[4];
        #pragma unroll
        for (int ct = 0; ct < 4; ++ct) {
            bhf[ct] = *(const short8*)&sBh[cur][(wc + ct * 16 + m) * 32 + rsw];
            blf[ct] = *(const short8*)&sBl[cur][(wc + ct * 16 + m) * 32 + rsw];
        }
        #pragma unroll
        for (int rt = 0; rt < 2; ++rt) {
            short8 ahf = *(const short8*)&sA[cur][(wr + rt * 16 + m) * 32 + rsw];
            #pragma unroll
            for (int ct = 0; ct < 4; ++ct) {
                acc[rt][ct] = __builtin_amdgcn_mfma_f32_16x16x32_bf16(ahf, bhf[ct], acc[rt][ct], 0, 0, 0);
                acc[rt][ct] = __builtin_amdgcn_mfma_f32_16x16x32_bf16(ahf, blf[ct], acc[rt][ct], 0, 0, 0);
            }
        }
        __syncthreads();
        cur ^= 1;
    }

    #pragma unroll
    for (int rt = 0; rt < 2; ++rt) {
        #pragma unroll
        for (int ct = 0; ct < 4; ++ct) {
            int ocol = col0 + wc + ct * 16 + m;
            float bb = bias[ocol];
            #pragma unroll
            for (int reg = 0; reg < 4; ++reg) {
                int orow = row0 + wr + rt * 16 + quad * 4 + reg;
                if (orow >= GN_N) continue;
                Obf[(size_t)orow * ldo + ocol] = f2bf_rne(acc[rt][ct][reg] + bb);
            }
        }
    }
}

// ---------------- CSR build ----------------
__global__ void zero_int(int* p, int n)
{
    int i = blockIdx.x * 256 + threadIdx.x;
    if (i < n) p[i] = 0;
}

__global__ void hist_kernel(const int* __restrict__ dst, int* __restrict__ deg)
{
    int e = blockIdx.x * 256 + threadIdx.x;
    if (e < GN_E) atomicAdd(&deg[dst[e]], 1);
}

__global__ void scan1(const int* __restrict__ deg, int* __restrict__ rp, int* __restrict__ bsums)
{
    __shared__ int s[256];
    int b = blockIdx.x, t = threadIdx.x;
    int i = b * 256 + t;
    int v = (i < GN_N) ? deg[i] : 0;
    s[t] = v;
    __syncthreads();
    for (int off = 1; off < 256; off <<= 1) {
        int x = (t >= off) ? s[t - off] : 0;
        __syncthreads();
        s[t] += x;
        __syncthreads();
    }
    if (i < GN_N) rp[i] = s[t] - v;
    if (t == 255) bsums[b] = s[255];
}

__global__ __launch_bounds__(512) void scan2(int* bsums, int nb)
{
    __shared__ int s[512];
    int t = threadIdx.x;
    int v = (t < nb) ? bsums[t] : 0;
    s[t] = v;
    __syncthreads();
    for (int off = 1; off < 512; off <<= 1) {
        int x = (t >= off) ? s[t - off] : 0;
        __syncthreads();
        s[t] += x;
        __syncthreads();
    }
    if (t < nb) bsums[t] = s[t] - v;
}

__global__ void scan3(const int* __restrict__ bsums, int* __restrict__ rp, int* __restrict__ cursor)
{
    int b = blockIdx.x, t = threadIdx.x;
    int i = b * 256 + t;
    if (i < GN_N) {
        int v = rp[i] + bsums[b];
        rp[i] = v; cursor[i] = v;
    }
    if (i == 0) rp[GN_N] = GN_E;
}

__global__ void scatter_kernel(
    const int* __restrict__ src, const int* __restrict__ dst,
    int* __restrict__ cursor, int* __restrict__ elist)
{
    int e = blockIdx.x * 256 + threadIdx.x;
    if (e >= GN_E) return;
    int d = dst[e];
    int pos = atomicAdd(&cursor[d], 1);
    elist[pos] = src[e];
}

__global__ void bounds_kernel(const int* __restrict__ batch, int* __restrict__ se)
{
    int i = blockIdx.x * 256 + threadIdx.x;
    if (i >= GN_N) return;
    int g = batch[i];
    if (i == 0 || batch[i - 1] != g) se[g] = i;
    if (i == GN_N - 1 || batch[i + 1] != g) se[32 + g] = i + 1;
}

// Layer-1 gather. Gbf row 256 = [K64|QV128|S64]. 4 nodes/wave, 8-edge batch.
// Writes leaky(h1_pre) bf16 [N][64].
__global__ __launch_bounds__(256, 2) void edge_gather_w(
    const ushort* __restrict__ Gbf, ushort* __restrict__ Abf,
    const int* __restrict__ row_ptr, const int* __restrict__ elist)
{
    int w = threadIdx.x >> 6, c = threadIdx.x & 63;
    int n0 = blockIdx.x * 16 + w * 4;

    float k[4], acc[4];
    int beg[4], end[4];
    #pragma unroll
    for (int j = 0; j < 4; ++j) {
        int node = n0 + j;
        bool ok = node < GN_N;
        int nd = ok ? node : 0;
        beg[j] = row_ptr[nd];
        end[j] = ok ? row_ptr[nd + 1] : beg[j];
        k[j]   = bf2f(Gbf[(size_t)nd * 256 + c]);
        acc[j] = bf2f(Gbf[(size_t)nd * 256 + 192 + c]);
    }
    int s[32];
    #pragma unroll
    for (int j = 0; j < 4; ++j) {
        #pragma unroll
        for (int e = 0; e < 8; ++e) {
            int idx = beg[j] + e;
            s[j * 8 + e] = elist[idx < end[j] ? idx : 0];
        }
    }
    uint qv[32];
    #pragma unroll
    for (int je = 0; je < 32; ++je)
        qv[je] = *(const uint*)&Gbf[(size_t)s[je] * 256 + 64 + 2 * c];
    #pragma unroll
    for (int j = 0; j < 4; ++j) {
        #pragma unroll
        for (int e = 0; e < 8; ++e) {
            if (beg[j] + e < end[j]) {
                uint p = qv[j * 8 + e];
                float gt = k[j] + bf2f((ushort)(p & 0xffffu));
                if (gt > 0.f) acc[j] += gt * bf2f((ushort)(p >> 16));
            }
        }
    }
    #pragma unroll
    for (int j = 0; j < 4; ++j) {
        for (int i = beg[j] + 8; i < end[j]; ++i) {
            int ss = elist[i];
            uint p = *(const uint*)&Gbf[(size_t)ss * 256 + 64 + 2 * c];
            float gt = k[j] + bf2f((ushort)(p & 0xffffu));
            if (gt > 0.f) acc[j] += gt * bf2f((ushort)(p >> 16));
        }
    }
    #pragma unroll
    for (int j = 0; j < 4; ++j)
        if (n0 + j < GN_N) {
            float a = acc[j];
            a = a > 0.f ? a : 0.01f * a;   // leaky here (fp32) -> gemm is pure copy
            Abf[(size_t)(n0 + j) * 64 + c] = f2bf_rne(a);
        }
}

// Layer-2 dual gather. Gbf row 512 = [K128|QV256|S128]; thread handles
// channels c and 64+c. Writes leaky(h2_pre) bf16 [N][128].
__global__ __launch_bounds__(256, 2) void edge_gather_w2(
    const ushort* __restrict__ Gbf, ushort* __restrict__ Abf,
    const int* __restrict__ row_ptr, const int* __restrict__ elist)
{
    int w = threadIdx.x >> 6, c = threadIdx.x & 63;
    int n0 = blockIdx.x * 16 + w * 4;

    float k0[4], k1[4], a0[4], a1[4];
    int beg[4], end[4];
    #pragma unroll
    for (int j = 0; j < 4; ++j) {
        int node = n0 + j;
        bool ok = node < GN_N;
        int nd = ok ? node : 0;
        beg[j] = row_ptr[nd];
        end[j] = ok ? row_ptr[nd + 1] : beg[j];
        size_t b = (size_t)nd * 512;
        k0[j] = bf2f(Gbf[b + c]);
        k1[j] = bf2f(Gbf[b + 64 + c]);
        a0[j] = bf2f(Gbf[b + 384 + c]);
        a1[j] = bf2f(Gbf[b + 448 + c]);
    }
    int s[32];
    #pragma unroll
    for (int j = 0; j < 4; ++j) {
        #pragma unroll
        for (int e = 0; e < 8; ++e) {
            int idx = beg[j] + e;
            s[j * 8 + e] = elist[idx < end[j] ? idx : 0];
        }
    }
    uint qv0[32], qv1[32];
    #pragma unroll
    for (int je = 0; je < 32; ++je) {
        size_t b = (size_t)s[je] * 512;
        qv0[je] = *(const uint*)&Gbf[b + 128 + 2 * c];
        qv1[je] = *(const uint*)&Gbf[b + 256 + 2 * c];
    }
    #pragma unroll
    for (int j = 0; j < 4; ++j) {
        #pragma unroll
        for (int e = 0; e < 8; ++e) {
            if (beg[j] + e < end[j]) {
                uint p = qv0[j * 8 + e];
                float gt = k0[j] + bf2f((ushort)(p & 0xffffu));
                if (gt > 0.f) a0[j] += gt * bf2f((ushort)(p >> 16));
                uint q = qv1[j * 8 + e];
                float gu = k1[j] + bf2f((ushort)(q & 0xffffu));
                if (gu > 0.f) a1[j] += gu * bf2f((ushort)(q >> 16));
            }
        }
    }
    #pragma unroll
    for (int j = 0; j < 4; ++j) {
        for (int i = beg[j] + 8; i < end[j]; ++i) {
            size_t b = (size_t)elist[i] * 512;
            uint p = *(const uint*)&Gbf[b + 128 + 2 * c];
            uint q = *(const uint*)&Gbf[b + 256 + 2 * c];
            float gt = k0[j] + bf2f((ushort)(p & 0xffffu));
            if (gt > 0.f) a0[j] += gt * bf2f((ushort)(p >> 16));
            float gu = k1[j] + bf2f((ushort)(q & 0xffffu));
            if (gu > 0.f) a1[j] += gu * bf2f((ushort)(q >> 16));
        }
    }
    #pragma unroll
    for (int j = 0; j < 4; ++j)
        if (n0 + j < GN_N) {
            float x = a0[j], y = a1[j];
            x = x > 0.f ? x : 0.01f * x;
            y = y > 0.f ? y : 0.01f * y;
            Abf[(size_t)(n0 + j) * 128 + c]      = f2bf_rne(x);
            Abf[(size_t)(n0 + j) * 128 + 64 + c] = f2bf_rne(y);
        }
}

// Layer-3 dual gather + leaky + pool. Gbf row 512; channels c0+c, c0+64+c.
__global__ __launch_bounds__(256, 2) void edge_gather_pool2(
    const ushort* __restrict__ Gbf,
    const int* __restrict__ row_ptr, const int* __restrict__ elist,
    const int* __restrict__ batch,
    float* __restrict__ sums, int c0)
{
    __shared__ float red[16][128];
    __shared__ int gid[16];
    int w = threadIdx.x >> 6, c = threadIdx.x & 63;
    int n0 = blockIdx.x * 16 + w * 4;

    float k0[4], k1[4], a0[4], a1[4];
    int beg[4], end[4];
    #pragma unroll
    for (int j = 0; j < 4; ++j) {
        int node = n0 + j;
        bool ok = node < GN_N;
        int nd = ok ? node : 0;
        beg[j] = row_ptr[nd];
        end[j] = ok ? row_ptr[nd + 1] : beg[j];
        size_t b = (size_t)nd * 512;
        k0[j] = bf2f(Gbf[b + c]);
        k1[j] = bf2f(Gbf[b + 64 + c]);
        a0[j] = ok ? bf2f(Gbf[b + 384 + c]) : 0.f;
        a1[j] = ok ? bf2f(Gbf[b + 448 + c]) : 0.f;
    }
    int s[32];
    #pragma unroll
    for (int j = 0; j < 4; ++j) {
        #pragma unroll
        for (int e = 0; e < 8; ++e) {
            int idx = beg[j] + e;
            s[j * 8 + e] = elist[idx < end[j] ? idx : 0];
        }
    }
    uint qv0[32], qv1[32];
    #pragma unroll
    for (int je = 0; je < 32; ++je) {
        size_t b = (size_t)s[je] * 512;
        qv0[je] = *(const uint*)&Gbf[b + 128 + 2 * c];
        qv1[je] = *(const uint*)&Gbf[b + 256 + 2 * c];
    }
    #pragma unroll
    for (int j = 0; j < 4; ++j) {
        #pragma unroll
        for (int e = 0; e < 8; ++e) {
            if (beg[j] + e < end[j]) {
                uint p = qv0[j * 8 + e];
                float gt = k0[j] + bf2f((ushort)(p & 0xffffu));
                if (gt > 0.f) a0[j] += gt * bf2f((ushort)(p >> 16));
                uint q = qv1[j * 8 + e];
                float gu = k1[j] + bf2f((ushort)(q & 0xffffu));
                if (gu > 0.f) a1[j] += gu * bf2f((ushort)(q >> 16));
            }
        }
    }
    #pragma unroll
    for (int j = 0; j < 4; ++j) {
        for (int i = beg[j] + 8; i < end[j]; ++i) {
            size_t b = (size_t)elist[i] * 512;
            uint p = *(const uint*)&Gbf[b + 128 + 2 * c];
            uint q = *(const uint*)&Gbf[b + 256 + 2 * c];
            float gt = k0[j] + bf2f((ushort)(p & 0xffffu));
            if (gt > 0.f) a0[j] += gt * bf2f((ushort)(p >> 16));
            float gu = k1[j] + bf2f((ushort)(q & 0xffffu));
            if (gu > 0.f) a1[j] += gu * bf2f((ushort)(q >> 16));
        }
    }
    #pragma unroll
    for (int j = 0; j < 4; ++j) {
        float x = a0[j], y = a1[j];
        red[w * 4 + j][c]      = x > 0.f ? x : 0.01f * x;
        red[w * 4 + j][64 + c] = y > 0.f ? y : 0.01f * y;
    }
    if (c < 4) {
        int node = n0 + c;
        gid[w * 4 + c] = (node < GN_N) ? batch[node] : -1;
    }
    __syncthreads();
    if (w == 0) {
        int stripe = blockIdx.x & 31;
        int i = 0;
        while (i < 16) {
            int gg = gid[i];
            float s0 = 0.f, s1 = 0.f;
            int j = i;
            while (j < 16 && gid[j] == gg) { s0 += red[j][c]; s1 += red[j][64 + c]; ++j; }
            if (gg >= 0) {
                float* dstp = &sums[(size_t)(stripe * GN_G + gg) * 256 + c0 + c];
                atomicAdd(dstp, s0);
                atomicAdd(dstp + 64, s1);
            }
            i = j;
        }
    }
}

// One block per graph: reduce 32 stripes; Pl = sums[g]/cnt[g] (cnt from se);
// Pg = Pl @ Wl3 + bl3; BN-MLP chain.
__global__ __launch_bounds__(256) void mlp_kernel(
    const float* __restrict__ sums, const int* __restrict__ se,
    const float* __restrict__ Wl3, const float* __restrict__ bl3,
    const float* __restrict__ W1, const float* __restrict__ b1,
    const float* __restrict__ Wh, const float* __restrict__ bh,
    const float* __restrict__ Wo, const float* __restrict__ bo,
    const float* __restrict__ gamma, const float* __restrict__ beta,
    const float* __restrict__ mean, const float* __restrict__ var,
    float* __restrict__ out)
{
    __shared__ float sp[256];
    __shared__ float pg[256];
    __shared__ float h0[64], h1[64];
    const int g = blockIdx.x;
    const int t = threadIdx.x;
    const float cntg = (float)(se[32 + g] - se[g]);
    const float inv = 1.0f / fmaxf(cntg, 1.0f);

    {
        float acc = 0.f;
        #pragma unroll 8
        for (int st = 0; st < 32; ++st)
            acc += sums[(size_t)(st * GN_G + g) * 256 + t];
        sp[t] = acc * inv;
    }
    __syncthreads();

    {
        float a0 = 0.f, a1 = 0.f, a2 = 0.f, a3 = 0.f;
        #pragma unroll 4
        for (int k = 0; k < 256; k += 4) {
            a0 += sp[k + 0] * Wl3[(k + 0) * 256 + t];
            a1 += sp[k + 1] * Wl3[(k + 1) * 256 + t];
            a2 += sp[k + 2] * Wl3[(k + 2) * 256 + t];
            a3 += sp[k + 3] * Wl3[(k + 3) * 256 + t];
        }
        pg[t] = bl3[t] + ((a0 + a1) + (a2 + a3));
    }
    __syncthreads();

    if (t < 64) {
        float a0 = 0.f, a1 = 0.f, a2 = 0.f, a3 = 0.f;
        #pragma unroll 4
        for (int k = 0; k < 256; k += 4) {
            a0 += pg[k + 0] * W1[(k + 0) * 64 + t];
            a1 += pg[k + 1] * W1[(k + 1) * 64 + t];
            a2 += pg[k + 2] * W1[(k + 2) * 64 + t];
            a3 += pg[k + 3] * W1[(k + 3) * 64 + t];
        }
        float acc = b1[t] + ((a0 + a1) + (a2 + a3));
        float sc = gamma[t] * rsqrtf(var[t] + 1e-5f);
        acc = (acc - mean[t]) * sc + beta[t];
        h0[t] = fmaxf(acc, 0.0f);
    }
    __syncthreads();

    for (int L = 0; L < 3; ++L) {
        const float* W  = Wh + L * 64 * 64;
        const float* hin  = (L & 1) ? h1 : h0;
        float*       hout = (L & 1) ? h0 : h1;
        if (t < 64) {
            const float* ga = gamma + (L + 1) * 64;
            const float* be = beta  + (L + 1) * 64;
            const float* me = mean  + (L + 1) * 64;
            const float* va = var   + (L + 1) * 64;
            float a0 = 0.f, a1 = 0.f, a2 = 0.f, a3 = 0.f;
            #pragma unroll 4
            for (int k = 0; k < 64; k += 4) {
                a0 += hin[k + 0] * W[(k + 0) * 64 + t];
                a1 += hin[k + 1] * W[(k + 1) * 64 + t];
                a2 += hin[k + 2] * W[(k + 2) * 64 + t];
                a3 += hin[k + 3] * W[(k + 3) * 64 + t];
            }
            float acc = (bh + L * 64)[t] + ((a0 + a1) + (a2 + a3));
            float sc = ga[t] * rsqrtf(va[t] + 1e-5f);
            acc = (acc - me[t]) * sc + be[t];
            hout[t] = fmaxf(acc, 0.0f);
        }
        __syncthreads();
    }

    if (t < 8) {
        const float* hf = h1;
        float acc = bo[t];
        for (int k = 0; k < 64; ++k) acc += hf[k] * Wo[k * 8 + t];
        out[g * 8 + t] = acc;
    }
}

extern "C" void kernel_launch(void* const* d_in, const int* in_sizes, int n_in,
                              void* d_out, int out_size, void* d_ws, size_t ws_size,
                              hipStream_t stream)
{
    const int N = GN_N, E = GN_E;
    const float* x          = (const float*)d_in[0];
    const int*   edge_index = (const int*)d_in[1];
    const int*   batch      = (const int*)d_in[2];
    const int*   src = edge_index;
    const int*   dst = edge_index + E;
    auto F = [&](int i) { return (const float*)d_in[i]; };

    // ---- workspace layout ----
    float* ws    = (float*)d_ws;
    float* sums  = ws;                          // 32 stripes x 32 x 256
    float* bcat  = sums + 32 * GN_G * 256;      // 1792
    ushort* Whi  = (ushort*)(bcat + 1792);
    ushort* Wlo  = Whi + W_TOTAL;
    ushort* xbf  = Wlo + W_TOTAL;               // N x 128 bf16
    ushort* h1bf = xbf + (size_t)N * 128;       // N x 64 bf16 (leaky'd)
    ushort* h2bf = h1bf + (size_t)N * 64;       // N x 128 bf16 (leaky'd)
    ushort* Gbf  = h2bf + (size_t)N * 128;      // N x 512 bf16
    int* deg     = (int*)(Gbf + (size_t)N * 512);
    int* cursor  = deg + N;
    int* row_ptr = cursor + N;                  // N+1
    int* elist   = row_ptr + (N + 1);           // E
    int* bsums   = elist + E;                   // 512
    int* se      = bsums + 512;                 // 64

    size_t need = (size_t)((char*)(se + 64) - (char*)ws);
    if (ws_size < need) return;

    // ---- CSR build + graph bounds ----
    const int eb = (E + 255) / 256;
    const int nb = (N + 255) / 256;
    zero_int<<<nb, 256, 0, stream>>>(deg, N);
    zero_int<<<1, 256, 0, stream>>>(se, 64);
    hist_kernel<<<eb, 256, 0, stream>>>(dst, deg);
    scan1<<<nb, 256, 0, stream>>>(deg, row_ptr, bsums);
    scan2<<<1, 512, 0, stream>>>(bsums, nb);
    scan3<<<nb, 256, 0, stream>>>(bsums, row_ptr, cursor);
    scatter_kernel<<<eb, 256, 0, stream>>>(src, dst, cursor, elist);
    bounds_kernel<<<nb, 256, 0, stream>>>(batch, se);

    // ---- weight prep: L1 pack; L2/L3 composed with previous Wl ----
    W1Src S1;
    for (int g = 0; g < 4; ++g) { S1.Wg[g] = F(3 + g); S1.bg[g] = F(7 + g); }
    wconv_l1<<<(32768 + 256 + 255) / 256, 256, 0, stream>>>(S1, Whi, Wlo, bcat);

    CSrc S2;
    S2.Wl = F(11); S2.bl = F(12);
    for (int g = 0; g < 4; ++g) { S2.Wg[g] = F(13 + g); S2.bg[g] = F(17 + g); }
    compose_l2<<<(512 * 64 + 255) / 256, 256, 0, stream>>>(S2, Whi, Wlo, bcat);

    CSrc S3;
    S3.Wl = F(21); S3.bl = F(22);
    for (int g = 0; g < 4; ++g) { S3.Wg[g] = F(23 + g); S3.bg[g] = F(27 + g); }
    compose_l3<<<(1024 * 128 + 255) / 256, 256, 0, stream>>>(S3, Whi, Wlo, bcat);

    aconv<<<(N * 16 + 255) / 256, 256, 0, stream>>>(x, xbf, sums);

    const int rb = (N + 127) / 128;
    const int gatherBlocks = (N + 15) / 16;

    // ---- layer 1 (256 cols: [K64|QV128|S64]) ----
    gemm2<<<dim3(2, rb), 512, 0, stream>>>(
        xbf, 128, Whi, Wlo, bcat, Gbf, 256, 128);
    edge_gather_w<<<gatherBlocks, 256, 0, stream>>>(Gbf, h1bf, row_ptr, elist);

    // ---- layer 2 (composed: leaky'd h1 @ Wl1Wg2; 512 cols, K=64) ----
    gemm2<<<dim3(4, rb), 512, 0, stream>>>(
        h1bf, 64, Whi + WOFF_L2, Wlo + WOFF_L2, bcat + 256, Gbf, 512, 64);
    edge_gather_w2<<<gatherBlocks, 256, 0, stream>>>(Gbf, h2bf, row_ptr, elist);

    // ---- layer 3 (composed: leaky'd h2 @ Wl2Wg3; 2 groups x 512, K=128) ----
    for (int ch = 0; ch < 2; ++ch) {
        size_t go = WOFF_L3 + (size_t)ch * 65536;
        gemm2<<<dim3(4, rb), 512, 0, stream>>>(
            h2bf, 128, Whi + go, Wlo + go, bcat + 768 + ch * 512, Gbf, 512, 128);
        edge_gather_pool2<<<gatherBlocks, 256, 0, stream>>>(
            Gbf, row_ptr, elist, batch, sums, ch * 128);
    }

    mlp_kernel<<<GN_G, 256, 0, stream>>>(sums, se, F(31), F(32),
                                         F(33), F(34), F(35), F(36), F(37), F(38),
                                         F(39), F(40), F(41), F(42),
                                         (float*)d_out);
}

// Round 12
// 611.985 us; speedup vs baseline: 1.4556x; 1.0417x over previous
//
#include <hip/hip_runtime.h>
#include <hip/hip_bf16.h>

// ---------------------------------------------------------------------------
// QuadraticGNN: 3x ResGatedGraphConv (ReLU gate, LeakyReLU 0.01, linear Wl)
//               -> global mean pool (32 graphs) -> 5-layer MLP with BN.
// Round 24:
//   - R23 green baseline reproduced (637us; gemm 66.2us, 0 conflicts).
//   - gemm2 BM 128->256 (SAME stage->compute->barrier structure, R19's):
//     barrier/drain cost per output byte halves; occupancy unchanged
//     (was reg-capped at 2 blocks/CU; new 64KB LDS also caps at 2;
//     64 AGPR + ~60 VGPR <= 128 -> 4 waves/SIMD). A staging = 2 DMA
//     issues/wave (wave-uniform dest + lane*16B, legal). XOR swizzle is
//     row-mod-8 invariant -> carries over unchanged.
//   - Dispatch fusion: wconv_l1+compose_l2+compose_l3+zero_sums+aconv
//     -> ONE range-partitioned prep kernel; two zero_ints merged.
//     21 -> 16 dispatches.
// ---------------------------------------------------------------------------

#define GN_N 100000
#define GN_E 300000
#define GN_G 32

typedef __attribute__((ext_vector_type(8))) short short8;
typedef __attribute__((ext_vector_type(4))) float floatx4;

__device__ inline ushort f2bf_rne(float f) {
    unsigned u = __float_as_uint(f);
    unsigned r = u + 0x7fffu + ((u >> 16) & 1u);
    return (ushort)(r >> 16);
}
__device__ inline float bf2f(ushort h) { return __uint_as_float(((unsigned)h) << 16); }

// W-array layout (ushort offsets), k-major [col][K] per segment.
// L1: 256 cols x K128 [K64|QV128|S64].
// L2 (composed Wl1@Wg2): 512 cols x K64 [K128|QV256|S128].
// L3 (composed Wl2@Wg3): 2 groups x 512 cols x K128 [K128|QV256|S128].
#define WOFF_L2   32768
#define WOFF_L3   65536
#define W_TOTAL   196608

// prep kernel segment bounds
#define PREP_L1   33024           // 32768 + 256
#define PREP_C2   (PREP_L1 + 32768)
#define PREP_C3   (PREP_C2 + 131072)
#define PREP_ZS   (PREP_C3 + 262144)
#define PREP_AC   (PREP_ZS + 1600000)

struct PrepAll {
    const float* W1g[4]; const float* b1g[4];
    const float* Wl1; const float* bl1;
    const float* W2g[4]; const float* b2g[4];
    const float* Wl2; const float* bl2;
    const float* W3g[4]; const float* b3g[4];
    const float* x;
};

// One dispatch: L1 weight pack | compose L2 | compose L3 | zero sums | x->bf16.
__global__ void prep(PrepAll P, ushort* __restrict__ hi, ushort* __restrict__ lo,
                     float* __restrict__ biascat, ushort* __restrict__ xbf,
                     float* __restrict__ sums)
{
    int id = blockIdx.x * 256 + threadIdx.x;
    if (id < 32768) {
        int g  = id >> 13;          // 4 gates x (64 cols x 128 k)
        int r2 = id & 8191;
        int c  = r2 >> 7;
        int k  = r2 & 127;
        float v = P.W1g[g][k * 64 + c];
        int colIdx = (g == 0) ? c : (g == 3) ? (192 + c) : (64 + 2 * c + (g - 1));
        int dst = colIdx * 128 + k;
        ushort h = f2bf_rne(v);
        hi[dst] = h; lo[dst] = f2bf_rne(v - bf2f(h));
    } else if (id < PREP_L1) {
        int p = id - 32768;
        int g, cc;
        if (p < 64)       { g = 0; cc = p; }
        else if (p < 192) { g = 1 + ((p - 64) & 1); cc = (p - 64) >> 1; }
        else              { g = 3; cc = p - 192; }
        biascat[p] = P.b1g[g][cc];
    } else if (id < PREP_C2) {
        int i = id - PREP_L1;       // 512 cols x K=64
        int p = i >> 6, k = i & 63;
        int g, cc;
        if (p < 128)      { g = 0; cc = p; }
        else if (p < 384) { g = 1 + ((p - 128) & 1); cc = (p - 128) >> 1; }
        else              { g = 3; cc = p - 384; }
        const float* wg = P.W2g[g];
        float acc = 0.f;
        #pragma unroll 8
        for (int j = 0; j < 64; ++j)
            acc += P.Wl1[k * 64 + j] * wg[j * 128 + cc];
        int dst = WOFF_L2 + p * 64 + k;
        ushort h = f2bf_rne(acc);
        hi[dst] = h; lo[dst] = f2bf_rne(acc - bf2f(h));
        if (k == 0) {
            float b = P.b2g[g][cc];
            #pragma unroll 8
            for (int j = 0; j < 64; ++j) b += P.bl1[j] * wg[j * 128 + cc];
            biascat[256 + p] = b;
        }
    } else if (id < PREP_C3) {
        int i = id - PREP_C2;       // 1024 cols x K=128
        int p = i >> 7, k = i & 127;
        int ch = p >> 9, pp = p & 511;
        int g, cc;
        if (pp < 128)      { g = 0; cc = pp; }
        else if (pp < 384) { g = 1 + ((pp - 128) & 1); cc = (pp - 128) >> 1; }
        else               { g = 3; cc = pp - 384; }
        int srcc = ch * 128 + cc;
        const float* wg = P.W3g[g];
        float acc = 0.f;
        #pragma unroll 8
        for (int j = 0; j < 128; ++j)
            acc += P.Wl2[k * 128 + j] * wg[j * 256 + srcc];
        int dst = WOFF_L3 + ch * 65536 + pp * 128 + k;
        ushort h = f2bf_rne(acc);
        hi[dst] = h; lo[dst] = f2bf_rne(acc - bf2f(h));
        if (k == 0) {
            float b = P.b3g[g][srcc];
            #pragma unroll 8
            for (int j = 0; j < 128; ++j) b += P.bl2[j] * wg[j * 256 + srcc];
            biascat[768 + ch * 512 + pp] = b;
        }
    } else if (id < PREP_ZS) {
        sums[id - PREP_C3] = 0.0f;
    } else if (id < PREP_AC) {
        int i = id - PREP_ZS;
        int r = i >> 4, cc = i & 15;
        const float* src = P.x + (size_t)r * 128 + cc * 8;
        short8 h;
        #pragma unroll
        for (int j = 0; j < 8; ++j) h[j] = (short)f2bf_rne(src[j]);
        *(short8*)&xbf[(size_t)r * 128 + cc * 8] = h;
    }
}

// GEMM: 256 rows x 128 cols per block, 512 threads / 8 waves, pure-copy A.
// global_load_lds(16B) staging into linear LDS double-buffer; per-lane
// source addresses pre-swizzled so reads (same XOR) are bank-balanced.
// Grid (ncb, rb256): col-fast dispatch so co-resident blocks share A.
__global__ __launch_bounds__(512) void gemm2(
    const ushort* __restrict__ Aptr, int lda,
    const ushort* __restrict__ Bh, const ushort* __restrict__ Bl,
    const float* __restrict__ bias,
    ushort* __restrict__ Obf, int ldo,
    int K)
{
    __shared__ ushort sA[2][8192];            // 256 rows x 32 ushorts
    __shared__ ushort sBh[2][4096], sBl[2][4096];

    const int tid  = threadIdx.x;
    const int w    = tid >> 6, lane = tid & 63;
    const int m    = lane & 15, quad = lane >> 4;
    const int row0 = blockIdx.y * 256;
    const int col0 = blockIdx.x * 128;
    const int wr   = (w >> 1) * 64;
    const int wc   = (w & 1) * 64;

    // staging: wave w covers A rows w*32..w*32+31 (2 issues) and B col
    // w*16+sub. lane -> (sub, kc); LDS unit u = row*4 + kc holds chunk
    // kc^((sub>>1)&3).
    const int sub = lane >> 2;
    const int kc  = lane & 3;
    const int kcs = kc ^ ((sub >> 1) & 3);
    const int arow0 = row0 + w * 32 + sub;
    const int arow1 = arow0 + 16;
    const int arow0c = arow0 < GN_N ? arow0 : 0;   // clamp: in-bounds DMA
    const int arow1c = arow1 < GN_N ? arow1 : 0;
    const ushort* aSrc0 = Aptr + (size_t)arow0c * lda + kcs * 8;
    const ushort* aSrc1 = Aptr + (size_t)arow1c * lda + kcs * 8;
    const ushort* bhSrc = Bh + (size_t)(col0 + w * 16 + sub) * K + kcs * 8;
    const ushort* blSrc = Bl + (size_t)(col0 + w * 16 + sub) * K + kcs * 8;

    floatx4 acc[4][4];
    #pragma unroll
    for (int i = 0; i < 4; ++i)
        #pragma unroll
        for (int j = 0; j < 4; ++j) acc[i][j] = (floatx4){0.f, 0.f, 0.f, 0.f};

    auto stage = [&](int buf, int k0) {
        __builtin_amdgcn_global_load_lds(
            (const __attribute__((address_space(1))) void*)(aSrc0 + k0),
            (__attribute__((address_space(3))) void*)&sA[buf][w * 1024], 16, 0, 0);
        __builtin_amdgcn_global_load_lds(
            (const __attribute__((address_space(1))) void*)(aSrc1 + k0),
            (__attribute__((address_space(3))) void*)&sA[buf][w * 1024 + 512], 16, 0, 0);
        __builtin_amdgcn_global_load_lds(
            (const __attribute__((address_space(1))) void*)(bhSrc + k0),
            (__attribute__((address_space(3))) void*)&sBh[buf][w * 512], 16, 0, 0);
        __builtin_amdgcn_global_load_lds(
            (const __attribute__((address_space(1))) void*)(blSrc + k0),
            (__attribute__((address_space(3))) void*)&sBl[buf][w * 512], 16, 0, 0);
    };

    const int nt = K >> 5;
    stage(0, 0);
    __syncthreads();

    const int rsw = (quad ^ ((m >> 1) & 3)) * 8;   // read-side swizzle (ushorts)
    int cur = 0;
    for (int t = 0; t < nt; ++t) {
        if (t + 1 < nt) stage(cur ^ 1, (t + 1) << 5);
        short8 bhf[4], blf[4];
        #pragma unroll
        for (int ct = 0; ct < 4; ++ct) {
            bhf[ct] = *(const short8*)&sBh[cur][(wc + ct * 16 + m) * 32 + rsw];
            blf[ct] = *(const short8*)&sBl[cur][(wc + ct * 16 + m) * 32 + rsw];
        }
        #pragma unroll
        for (int rt = 0; rt < 4; ++rt) {
            short8 ahf = *(const short8*)&sA[cur][(wr + rt * 16 + m) * 32 + rsw];
            #pragma unroll
            for (int ct = 0; ct < 4; ++ct) {
                acc[rt][ct] = __builtin_amdgcn_mfma_f32_16x16x32_bf16(ahf, bhf[ct], acc[rt][ct], 0, 0, 0);
                acc[rt][ct] = __builtin_amdgcn_mfma_f32_16x16x32_bf16(ahf, blf[ct], acc[rt][ct], 0, 0, 0);
            }
        }
        __syncthreads();
        cur ^= 1;
    }

    #pragma unroll
    for (int rt = 0; rt < 4; ++rt) {
        #pragma unroll
        for (int ct = 0; ct < 4; ++ct) {
            int ocol = col0 + wc + ct * 16 + m;
            float bb = bias[ocol];
            #pragma unroll
            for (int reg = 0; reg < 4; ++reg) {
                int orow = row0 + wr + rt * 16 + quad * 4 + reg;
                if (orow >= GN_N) continue;
                Obf[(size_t)orow * ldo + ocol] = f2bf_rne(acc[rt][ct][reg] + bb);
            }
        }
    }
}

// ---------------- CSR build ----------------
__global__ void zero_ds(int* __restrict__ deg, int* __restrict__ se)
{
    int i = blockIdx.x * 256 + threadIdx.x;
    if (i < GN_N) deg[i] = 0;
    else if (i < GN_N + 64) se[i - GN_N] = 0;
}

__global__ void hist_kernel(const int* __restrict__ dst, int* __restrict__ deg)
{
    int e = blockIdx.x * 256 + threadIdx.x;
    if (e < GN_E) atomicAdd(&deg[dst[e]], 1);
}

__global__ void scan1(const int* __restrict__ deg, int* __restrict__ rp, int* __restrict__ bsums)
{
    __shared__ int s[256];
    int b = blockIdx.x, t = threadIdx.x;
    int i = b * 256 + t;
    int v = (i < GN_N) ? deg[i] : 0;
    s[t] = v;
    __syncthreads();
    for (int off = 1; off < 256; off <<= 1) {
        int x = (t >= off) ? s[t - off] : 0;
        __syncthreads();
        s[t] += x;
        __syncthreads();
    }
    if (i < GN_N) rp[i] = s[t] - v;
    if (t == 255) bsums[b] = s[255];
}

__global__ __launch_bounds__(512) void scan2(int* bsums, int nb)
{
    __shared__ int s[512];
    int t = threadIdx.x;
    int v = (t < nb) ? bsums[t] : 0;
    s[t] = v;
    __syncthreads();
    for (int off = 1; off < 512; off <<= 1) {
        int x = (t >= off) ? s[t - off] : 0;
        __syncthreads();
        s[t] += x;
        __syncthreads();
    }
    if (t < nb) bsums[t] = s[t] - v;
}

__global__ void scan3(const int* __restrict__ bsums, int* __restrict__ rp, int* __restrict__ cursor)
{
    int b = blockIdx.x, t = threadIdx.x;
    int i = b * 256 + t;
    if (i < GN_N) {
        int v = rp[i] + bsums[b];
        rp[i] = v; cursor[i] = v;
    }
    if (i == 0) rp[GN_N] = GN_E;
}

__global__ void scatter_kernel(
    const int* __restrict__ src, const int* __restrict__ dst,
    int* __restrict__ cursor, int* __restrict__ elist)
{
    int e = blockIdx.x * 256 + threadIdx.x;
    if (e >= GN_E) return;
    int d = dst[e];
    int pos = atomicAdd(&cursor[d], 1);
    elist[pos] = src[e];
}

__global__ void bounds_kernel(const int* __restrict__ batch, int* __restrict__ se)
{
    int i = blockIdx.x * 256 + threadIdx.x;
    if (i >= GN_N) return;
    int g = batch[i];
    if (i == 0 || batch[i - 1] != g) se[g] = i;
    if (i == GN_N - 1 || batch[i + 1] != g) se[32 + g] = i + 1;
}

// Layer-1 gather. Gbf row 256 = [K64|QV128|S64]. 4 nodes/wave, 8-edge batch.
// Writes leaky(h1_pre) bf16 [N][64].
__global__ __launch_bounds__(256, 2) void edge_gather_w(
    const ushort* __restrict__ Gbf, ushort* __restrict__ Abf,
    const int* __restrict__ row_ptr, const int* __restrict__ elist)
{
    int w = threadIdx.x >> 6, c = threadIdx.x & 63;
    int n0 = blockIdx.x * 16 + w * 4;

    float k[4], acc[4];
    int beg[4], end[4];
    #pragma unroll
    for (int j = 0; j < 4; ++j) {
        int node = n0 + j;
        bool ok = node < GN_N;
        int nd = ok ? node : 0;
        beg[j] = row_ptr[nd];
        end[j] = ok ? row_ptr[nd + 1] : beg[j];
        k[j]   = bf2f(Gbf[(size_t)nd * 256 + c]);
        acc[j] = bf2f(Gbf[(size_t)nd * 256 + 192 + c]);
    }
    int s[32];
    #pragma unroll
    for (int j = 0; j < 4; ++j) {
        #pragma unroll
        for (int e = 0; e < 8; ++e) {
            int idx = beg[j] + e;
            s[j * 8 + e] = elist[idx < end[j] ? idx : 0];
        }
    }
    uint qv[32];
    #pragma unroll
    for (int je = 0; je < 32; ++je)
        qv[je] = *(const uint*)&Gbf[(size_t)s[je] * 256 + 64 + 2 * c];
    #pragma unroll
    for (int j = 0; j < 4; ++j) {
        #pragma unroll
        for (int e = 0; e < 8; ++e) {
            if (beg[j] + e < end[j]) {
                uint p = qv[j * 8 + e];
                float gt = k[j] + bf2f((ushort)(p & 0xffffu));
                if (gt > 0.f) acc[j] += gt * bf2f((ushort)(p >> 16));
            }
        }
    }
    #pragma unroll
    for (int j = 0; j < 4; ++j) {
        for (int i = beg[j] + 8; i < end[j]; ++i) {
            int ss = elist[i];
            uint p = *(const uint*)&Gbf[(size_t)ss * 256 + 64 + 2 * c];
            float gt = k[j] + bf2f((ushort)(p & 0xffffu));
            if (gt > 0.f) acc[j] += gt * bf2f((ushort)(p >> 16));
        }
    }
    #pragma unroll
    for (int j = 0; j < 4; ++j)
        if (n0 + j < GN_N) {
            float a = acc[j];
            a = a > 0.f ? a : 0.01f * a;   // leaky here (fp32) -> gemm is pure copy
            Abf[(size_t)(n0 + j) * 64 + c] = f2bf_rne(a);
        }
}

// Layer-2 dual gather. Gbf row 512 = [K128|QV256|S128]; thread handles
// channels c and 64+c. Writes leaky(h2_pre) bf16 [N][128].
__global__ __launch_bounds__(256, 2) void edge_gather_w2(
    const ushort* __restrict__ Gbf, ushort* __restrict__ Abf,
    const int* __restrict__ row_ptr, const int* __restrict__ elist)
{
    int w = threadIdx.x >> 6, c = threadIdx.x & 63;
    int n0 = blockIdx.x * 16 + w * 4;

    float k0[4], k1[4], a0[4], a1[4];
    int beg[4], end[4];
    #pragma unroll
    for (int j = 0; j < 4; ++j) {
        int node = n0 + j;
        bool ok = node < GN_N;
        int nd = ok ? node : 0;
        beg[j] = row_ptr[nd];
        end[j] = ok ? row_ptr[nd + 1] : beg[j];
        size_t b = (size_t)nd * 512;
        k0[j] = bf2f(Gbf[b + c]);
        k1[j] = bf2f(Gbf[b + 64 + c]);
        a0[j] = bf2f(Gbf[b + 384 + c]);
        a1[j] = bf2f(Gbf[b + 448 + c]);
    }
    int s[32];
    #pragma unroll
    for (int j = 0; j < 4; ++j) {
        #pragma unroll
        for (int e = 0; e < 8; ++e) {
            int idx = beg[j] + e;
            s[j * 8 + e] = elist[idx < end[j] ? idx : 0];
        }
    }
    uint qv0[32], qv1[32];
    #pragma unroll
    for (int je = 0; je < 32; ++je) {
        size_t b = (size_t)s[je] * 512;
        qv0[je] = *(const uint*)&Gbf[b + 128 + 2 * c];
        qv1[je] = *(const uint*)&Gbf[b + 256 + 2 * c];
    }
    #pragma unroll
    for (int j = 0; j < 4; ++j) {
        #pragma unroll
        for (int e = 0; e < 8; ++e) {
            if (beg[j] + e < end[j]) {
                uint p = qv0[j * 8 + e];
                float gt = k0[j] + bf2f((ushort)(p & 0xffffu));
                if (gt > 0.f) a0[j] += gt * bf2f((ushort)(p >> 16));
                uint q = qv1[j * 8 + e];
                float gu = k1[j] + bf2f((ushort)(q & 0xffffu));
                if (gu > 0.f) a1[j] += gu * bf2f((ushort)(q >> 16));
            }
        }
    }
    #pragma unroll
    for (int j = 0; j < 4; ++j) {
        for (int i = beg[j] + 8; i < end[j]; ++i) {
            size_t b = (size_t)elist[i] * 512;
            uint p = *(const uint*)&Gbf[b + 128 + 2 * c];
            uint q = *(const uint*)&Gbf[b + 256 + 2 * c];
            float gt = k0[j] + bf2f((ushort)(p & 0xffffu));
            if (gt > 0.f) a0[j] += gt * bf2f((ushort)(p >> 16));
            float gu = k1[j] + bf2f((ushort)(q & 0xffffu));
            if (gu > 0.f) a1[j] += gu * bf2f((ushort)(q >> 16));
        }
    }
    #pragma unroll
    for (int j = 0; j < 4; ++j)
        if (n0 + j < GN_N) {
            float x = a0[j], y = a1[j];
            x = x > 0.f ? x : 0.01f * x;
            y = y > 0.f ? y : 0.01f * y;
            Abf[(size_t)(n0 + j) * 128 + c]      = f2bf_rne(x);
            Abf[(size_t)(n0 + j) * 128 + 64 + c] = f2bf_rne(y);
        }
}

// Layer-3 dual gather + leaky + pool. Gbf row 512; channels c0+c, c0+64+c.
__global__ __launch_bounds__(256, 2) void edge_gather_pool2(
    const ushort* __restrict__ Gbf,
    const int* __restrict__ row_ptr, const int* __restrict__ elist,
    const int* __restrict__ batch,
    float* __restrict__ sums, int c0)
{
    __shared__ float red[16][128];
    __shared__ int gid[16];
    int w = threadIdx.x >> 6, c = threadIdx.x & 63;
    int n0 = blockIdx.x * 16 + w * 4;

    float k0[4], k1[4], a0[4], a1[4];
    int beg[4], end[4];
    #pragma unroll
    for (int j = 0; j < 4; ++j) {
        int node = n0 + j;
        bool ok = node < GN_N;
        int nd = ok ? node : 0;
        beg[j] = row_ptr[nd];
        end[j] = ok ? row_ptr[nd + 1] : beg[j];
        size_t b = (size_t)nd * 512;
        k0[j] = bf2f(Gbf[b + c]);
        k1[j] = bf2f(Gbf[b + 64 + c]);
        a0[j] = ok ? bf2f(Gbf[b + 384 + c]) : 0.f;
        a1[j] = ok ? bf2f(Gbf[b + 448 + c]) : 0.f;
    }
    int s[32];
    #pragma unroll
    for (int j = 0; j < 4; ++j) {
        #pragma unroll
        for (int e = 0; e < 8; ++e) {
            int idx = beg[j] + e;
            s[j * 8 + e] = elist[idx < end[j] ? idx : 0];
        }
    }
    uint qv0[32], qv1[32];
    #pragma unroll
    for (int je = 0; je < 32; ++je) {
        size_t b = (size_t)s[je] * 512;
        qv0[je] = *(const uint*)&Gbf[b + 128 + 2 * c];
        qv1[je] = *(const uint*)&Gbf[b + 256 + 2 * c];
    }
    #pragma unroll
    for (int j = 0; j < 4; ++j) {
        #pragma unroll
        for (int e = 0; e < 8; ++e) {
            if (beg[j] + e < end[j]) {
                uint p = qv0[j * 8 + e];
                float gt = k0[j] + bf2f((ushort)(p & 0xffffu));
                if (gt > 0.f) a0[j] += gt * bf2f((ushort)(p >> 16));
                uint q = qv1[j * 8 + e];
                float gu = k1[j] + bf2f((ushort)(q & 0xffffu));
                if (gu > 0.f) a1[j] += gu * bf2f((ushort)(q >> 16));
            }
        }
    }
    #pragma unroll
    for (int j = 0; j < 4; ++j) {
        for (int i = beg[j] + 8; i < end[j]; ++i) {
            size_t b = (size_t)elist[i] * 512;
            uint p = *(const uint*)&Gbf[b + 128 + 2 * c];
            uint q = *(const uint*)&Gbf[b + 256 + 2 * c];
            float gt = k0[j] + bf2f((ushort)(p & 0xffffu));
            if (gt > 0.f) a0[j] += gt * bf2f((ushort)(p >> 16));
            float gu = k1[j] + bf2f((ushort)(q & 0xffffu));
            if (gu > 0.f) a1[j] += gu * bf2f((ushort)(q >> 16));
        }
    }
    #pragma unroll
    for (int j = 0; j < 4; ++j) {
        float x = a0[j], y = a1[j];
        red[w * 4 + j][c]      = x > 0.f ? x : 0.01f * x;
        red[w * 4 + j][64 + c] = y > 0.f ? y : 0.01f * y;
    }
    if (c < 4) {
        int node = n0 + c;
        gid[w * 4 + c] = (node < GN_N) ? batch[node] : -1;
    }
    __syncthreads();
    if (w == 0) {
        int stripe = blockIdx.x & 31;
        int i = 0;
        while (i < 16) {
            int gg = gid[i];
            float s0 = 0.f, s1 = 0.f;
            int j = i;
            while (j < 16 && gid[j] == gg) { s0 += red[j][c]; s1 += red[j][64 + c]; ++j; }
            if (gg >= 0) {
                float* dstp = &sums[(size_t)(stripe * GN_G + gg) * 256 + c0 + c];
                atomicAdd(dstp, s0);
                atomicAdd(dstp + 64, s1);
            }
            i = j;
        }
    }
}

// One block per graph: reduce 32 stripes; Pl = sums[g]/cnt[g] (cnt from se);
// Pg = Pl @ Wl3 + bl3; BN-MLP chain.
__global__ __launch_bounds__(256) void mlp_kernel(
    const float* __restrict__ sums, const int* __restrict__ se,
    const float* __restrict__ Wl3, const float* __restrict__ bl3,
    const float* __restrict__ W1, const float* __restrict__ b1,
    const float* __restrict__ Wh, const float* __restrict__ bh,
    const float* __restrict__ Wo, const float* __restrict__ bo,
    const float* __restrict__ gamma, const float* __restrict__ beta,
    const float* __restrict__ mean, const float* __restrict__ var,
    float* __restrict__ out)
{
    __shared__ float sp[256];
    __shared__ float pg[256];
    __shared__ float h0[64], h1[64];
    const int g = blockIdx.x;
    const int t = threadIdx.x;
    const float cntg = (float)(se[32 + g] - se[g]);
    const float inv = 1.0f / fmaxf(cntg, 1.0f);

    {
        float acc = 0.f;
        #pragma unroll 8
        for (int st = 0; st < 32; ++st)
            acc += sums[(size_t)(st * GN_G + g) * 256 + t];
        sp[t] = acc * inv;
    }
    __syncthreads();

    {
        float a0 = 0.f, a1 = 0.f, a2 = 0.f, a3 = 0.f;
        #pragma unroll 4
        for (int k = 0; k < 256; k += 4) {
            a0 += sp[k + 0] * Wl3[(k + 0) * 256 + t];
            a1 += sp[k + 1] * Wl3[(k + 1) * 256 + t];
            a2 += sp[k + 2] * Wl3[(k + 2) * 256 + t];
            a3 += sp[k + 3] * Wl3[(k + 3) * 256 + t];
        }
        pg[t] = bl3[t] + ((a0 + a1) + (a2 + a3));
    }
    __syncthreads();

    if (t < 64) {
        float a0 = 0.f, a1 = 0.f, a2 = 0.f, a3 = 0.f;
        #pragma unroll 4
        for (int k = 0; k < 256; k += 4) {
            a0 += pg[k + 0] * W1[(k + 0) * 64 + t];
            a1 += pg[k + 1] * W1[(k + 1) * 64 + t];
            a2 += pg[k + 2] * W1[(k + 2) * 64 + t];
            a3 += pg[k + 3] * W1[(k + 3) * 64 + t];
        }
        float acc = b1[t] + ((a0 + a1) + (a2 + a3));
        float sc = gamma[t] * rsqrtf(var[t] + 1e-5f);
        acc = (acc - mean[t]) * sc + beta[t];
        h0[t] = fmaxf(acc, 0.0f);
    }
    __syncthreads();

    for (int L = 0; L < 3; ++L) {
        const float* W  = Wh + L * 64 * 64;
        const float* hin  = (L & 1) ? h1 : h0;
        float*       hout = (L & 1) ? h0 : h1;
        if (t < 64) {
            const float* ga = gamma + (L + 1) * 64;
            const float* be = beta  + (L + 1) * 64;
            const float* me = mean  + (L + 1) * 64;
            const float* va = var   + (L + 1) * 64;
            float a0 = 0.f, a1 = 0.f, a2 = 0.f, a3 = 0.f;
            #pragma unroll 4
            for (int k = 0; k < 64; k += 4) {
                a0 += hin[k + 0] * W[(k + 0) * 64 + t];
                a1 += hin[k + 1] * W[(k + 1) * 64 + t];
                a2 += hin[k + 2] * W[(k + 2) * 64 + t];
                a3 += hin[k + 3] * W[(k + 3) * 64 + t];
            }
            float acc = (bh + L * 64)[t] + ((a0 + a1) + (a2 + a3));
            float sc = ga[t] * rsqrtf(va[t] + 1e-5f);
            acc = (acc - me[t]) * sc + be[t];
            hout[t] = fmaxf(acc, 0.0f);
        }
        __syncthreads();
    }

    if (t < 8) {
        const float* hf = h1;
        float acc = bo[t];
        for (int k = 0; k < 64; ++k) acc += hf[k] * Wo[k * 8 + t];
        out[g * 8 + t] = acc;
    }
}

extern "C" void kernel_launch(void* const* d_in, const int* in_sizes, int n_in,
                              void* d_out, int out_size, void* d_ws, size_t ws_size,
                              hipStream_t stream)
{
    const int N = GN_N, E = GN_E;
    const int*   edge_index = (const int*)d_in[1];
    const int*   batch      = (const int*)d_in[2];
    const int*   src = edge_index;
    const int*   dst = edge_index + E;
    auto F = [&](int i) { return (const float*)d_in[i]; };

    // ---- workspace layout ----
    float* ws    = (float*)d_ws;
    float* sums  = ws;                          // 32 stripes x 32 x 256
    float* bcat  = sums + 32 * GN_G * 256;      // 1792
    ushort* Whi  = (ushort*)(bcat + 1792);
    ushort* Wlo  = Whi + W_TOTAL;
    ushort* xbf  = Wlo + W_TOTAL;               // N x 128 bf16
    ushort* h1bf = xbf + (size_t)N * 128;       // N x 64 bf16 (leaky'd)
    ushort* h2bf = h1bf + (size_t)N * 64;       // N x 128 bf16 (leaky'd)
    ushort* Gbf  = h2bf + (size_t)N * 128;      // N x 512 bf16
    int* deg     = (int*)(Gbf + (size_t)N * 512);
    int* cursor  = deg + N;
    int* row_ptr = cursor + N;                  // N+1
    int* elist   = row_ptr + (N + 1);           // E
    int* bsums   = elist + E;                   // 512
    int* se      = bsums + 512;                 // 64

    size_t need = (size_t)((char*)(se + 64) - (char*)ws);
    if (ws_size < need) return;

    // ---- CSR build + graph bounds ----
    const int eb = (E + 255) / 256;
    const int nb = (N + 255) / 256;
    zero_ds<<<(N + 64 + 255) / 256, 256, 0, stream>>>(deg, se);
    hist_kernel<<<eb, 256, 0, stream>>>(dst, deg);
    scan1<<<nb, 256, 0, stream>>>(deg, row_ptr, bsums);
    scan2<<<1, 512, 0, stream>>>(bsums, nb);
    scan3<<<nb, 256, 0, stream>>>(bsums, row_ptr, cursor);
    scatter_kernel<<<eb, 256, 0, stream>>>(src, dst, cursor, elist);
    bounds_kernel<<<nb, 256, 0, stream>>>(batch, se);

    // ---- fused prep: weight packs + composes + zero sums + x->bf16 ----
    PrepAll P;
    for (int g = 0; g < 4; ++g) { P.W1g[g] = F(3 + g);  P.b1g[g] = F(7 + g); }
    P.Wl1 = F(11); P.bl1 = F(12);
    for (int g = 0; g < 4; ++g) { P.W2g[g] = F(13 + g); P.b2g[g] = F(17 + g); }
    P.Wl2 = F(21); P.bl2 = F(22);
    for (int g = 0; g < 4; ++g) { P.W3g[g] = F(23 + g); P.b3g[g] = F(27 + g); }
    P.x = F(0);
    prep<<<(PREP_AC + 255) / 256, 256, 0, stream>>>(P, Whi, Wlo, bcat, xbf, sums);

    const int rb = (N + 255) / 256;
    const int gatherBlocks = (N + 15) / 16;

    // ---- layer 1 (256 cols: [K64|QV128|S64]) ----
    gemm2<<<dim3(2, rb), 512, 0, stream>>>(
        xbf, 128, Whi, Wlo, bcat, Gbf, 256, 128);
    edge_gather_w<<<gatherBlocks, 256, 0, stream>>>(Gbf, h1bf, row_ptr, elist);

    // ---- layer 2 (composed: leaky'd h1 @ Wl1Wg2; 512 cols, K=64) ----
    gemm2<<<dim3(4, rb), 512, 0, stream>>>(
        h1bf, 64, Whi + WOFF_L2, Wlo + WOFF_L2, bcat + 256, Gbf, 512, 64);
    edge_gather_w2<<<gatherBlocks, 256, 0, stream>>>(Gbf, h2bf, row_ptr, elist);

    // ---- layer 3 (composed: leaky'd h2 @ Wl2Wg3; 2 groups x 512, K=128) ----
    for (int ch = 0; ch < 2; ++ch) {
        size_t go = WOFF_L3 + (size_t)ch * 65536;
        gemm2<<<dim3(4, rb), 512, 0, stream>>>(
            h2bf, 128, Whi + go, Wlo + go, bcat + 768 + ch * 512, Gbf, 512, 128);
        edge_gather_pool2<<<gatherBlocks, 256, 0, stream>>>(
            Gbf, row_ptr, elist, batch, sums, ch * 128);
    }

    mlp_kernel<<<GN_G, 256, 0, stream>>>(sums, se, F(31), F(32),
                                         F(33), F(34), F(35), F(36), F(37), F(38),
                                         F(39), F(40), F(41), F(42),
                                         (float*)d_out);
}

// Round 13
// 594.726 us; speedup vs baseline: 1.4978x; 1.0290x over previous
//
#include <hip/hip_runtime.h>
#include <hip/hip_bf16.h>

// ---------------------------------------------------------------------------
// QuadraticGNN: 3x ResGatedGraphConv (ReLU gate, LeakyReLU 0.01, linear Wl)
//               -> global mean pool (32 graphs) -> 5-layer MLP with BN.
// Round 25:
//   - R24 green: 612us; gemm 59.1us @2.65TB/s, FETCH=2xA (col-fast grid
//     spreads same-row blocks over XCDs; L3 absorbs only half the re-read).
//   - T1 bijective XCD swizzle (m204) on a flattened 1D gemm grid: each
//     XCD owns a contiguous chunk of row panels incl. ALL their col-blocks
//     -> every A panel fetched from HBM once, Gbf writes XCD-local.
//     Pure index permutation (bijection proven), sync structure untouched.
//   - bounds_kernel folded into prep (depends only on batch; se zeroed in
//     dispatch 1, written in prep, read in mlp). 15 -> 14 dispatches.
// ---------------------------------------------------------------------------

#define GN_N 100000
#define GN_E 300000
#define GN_G 32

typedef __attribute__((ext_vector_type(8))) short short8;
typedef __attribute__((ext_vector_type(4))) float floatx4;

__device__ inline ushort f2bf_rne(float f) {
    unsigned u = __float_as_uint(f);
    unsigned r = u + 0x7fffu + ((u >> 16) & 1u);
    return (ushort)(r >> 16);
}
__device__ inline float bf2f(ushort h) { return __uint_as_float(((unsigned)h) << 16); }

// W-array layout (ushort offsets), k-major [col][K] per segment.
// L1: 256 cols x K128 [K64|QV128|S64].
// L2 (composed Wl1@Wg2): 512 cols x K64 [K128|QV256|S128].
// L3 (composed Wl2@Wg3): 2 groups x 512 cols x K128 [K128|QV256|S128].
#define WOFF_L2   32768
#define WOFF_L3   65536
#define W_TOTAL   196608

// prep kernel segment bounds
#define PREP_L1   33024           // 32768 + 256
#define PREP_C2   (PREP_L1 + 32768)
#define PREP_C3   (PREP_C2 + 131072)
#define PREP_ZS   (PREP_C3 + 262144)
#define PREP_AC   (PREP_ZS + 1600000)
#define PREP_BD   (PREP_AC + GN_N)

struct PrepAll {
    const float* W1g[4]; const float* b1g[4];
    const float* Wl1; const float* bl1;
    const float* W2g[4]; const float* b2g[4];
    const float* Wl2; const float* bl2;
    const float* W3g[4]; const float* b3g[4];
    const float* x;
    const int* batch;
};

// One dispatch: L1 pack | compose L2 | compose L3 | zero sums | x->bf16 | bounds.
__global__ void prep(PrepAll P, ushort* __restrict__ hi, ushort* __restrict__ lo,
                     float* __restrict__ biascat, ushort* __restrict__ xbf,
                     float* __restrict__ sums, int* __restrict__ se)
{
    int id = blockIdx.x * 256 + threadIdx.x;
    if (id < 32768) {
        int g  = id >> 13;          // 4 gates x (64 cols x 128 k)
        int r2 = id & 8191;
        int c  = r2 >> 7;
        int k  = r2 & 127;
        float v = P.W1g[g][k * 64 + c];
        int colIdx = (g == 0) ? c : (g == 3) ? (192 + c) : (64 + 2 * c + (g - 1));
        int dst = colIdx * 128 + k;
        ushort h = f2bf_rne(v);
        hi[dst] = h; lo[dst] = f2bf_rne(v - bf2f(h));
    } else if (id < PREP_L1) {
        int p = id - 32768;
        int g, cc;
        if (p < 64)       { g = 0; cc = p; }
        else if (p < 192) { g = 1 + ((p - 64) & 1); cc = (p - 64) >> 1; }
        else              { g = 3; cc = p - 192; }
        biascat[p] = P.b1g[g][cc];
    } else if (id < PREP_C2) {
        int i = id - PREP_L1;       // 512 cols x K=64
        int p = i >> 6, k = i & 63;
        int g, cc;
        if (p < 128)      { g = 0; cc = p; }
        else if (p < 384) { g = 1 + ((p - 128) & 1); cc = (p - 128) >> 1; }
        else              { g = 3; cc = p - 384; }
        const float* wg = P.W2g[g];
        float acc = 0.f;
        #pragma unroll 8
        for (int j = 0; j < 64; ++j)
            acc += P.Wl1[k * 64 + j] * wg[j * 128 + cc];
        int dst = WOFF_L2 + p * 64 + k;
        ushort h = f2bf_rne(acc);
        hi[dst] = h; lo[dst] = f2bf_rne(acc - bf2f(h));
        if (k == 0) {
            float b = P.b2g[g][cc];
            #pragma unroll 8
            for (int j = 0; j < 64; ++j) b += P.bl1[j] * wg[j * 128 + cc];
            biascat[256 + p] = b;
        }
    } else if (id < PREP_C3) {
        int i = id - PREP_C2;       // 1024 cols x K=128
        int p = i >> 7, k = i & 127;
        int ch = p >> 9, pp = p & 511;
        int g, cc;
        if (pp < 128)      { g = 0; cc = pp; }
        else if (pp < 384) { g = 1 + ((pp - 128) & 1); cc = (pp - 128) >> 1; }
        else               { g = 3; cc = pp - 384; }
        int srcc = ch * 128 + cc;
        const float* wg = P.W3g[g];
        float acc = 0.f;
        #pragma unroll 8
        for (int j = 0; j < 128; ++j)
            acc += P.Wl2[k * 128 + j] * wg[j * 256 + srcc];
        int dst = WOFF_L3 + ch * 65536 + pp * 128 + k;
        ushort h = f2bf_rne(acc);
        hi[dst] = h; lo[dst] = f2bf_rne(acc - bf2f(h));
        if (k == 0) {
            float b = P.b3g[g][srcc];
            #pragma unroll 8
            for (int j = 0; j < 128; ++j) b += P.bl2[j] * wg[j * 256 + srcc];
            biascat[768 + ch * 512 + pp] = b;
        }
    } else if (id < PREP_ZS) {
        sums[id - PREP_C3] = 0.0f;
    } else if (id < PREP_AC) {
        int i = id - PREP_ZS;
        int r = i >> 4, cc = i & 15;
        const float* src = P.x + (size_t)r * 128 + cc * 8;
        short8 h;
        #pragma unroll
        for (int j = 0; j < 8; ++j) h[j] = (short)f2bf_rne(src[j]);
        *(short8*)&xbf[(size_t)r * 128 + cc * 8] = h;
    } else if (id < PREP_BD) {
        int i = id - PREP_AC;
        int g = P.batch[i];
        if (i == 0 || P.batch[i - 1] != g) se[g] = i;
        if (i == GN_N - 1 || P.batch[i + 1] != g) se[32 + g] = i + 1;
    }
}

// GEMM: 256 rows x 128 cols per block, 512 threads / 8 waves, pure-copy A.
// global_load_lds(16B) staging into linear LDS double-buffer; per-lane
// source addresses pre-swizzled so reads (same XOR) are bank-balanced.
// 1D grid + bijective XCD swizzle (m204): each XCD owns contiguous row
// panels (all their col-blocks) -> A fetched from HBM once.
__global__ __launch_bounds__(512) void gemm2(
    const ushort* __restrict__ Aptr, int lda,
    const ushort* __restrict__ Bh, const ushort* __restrict__ Bl,
    const float* __restrict__ bias,
    ushort* __restrict__ Obf, int ldo,
    int K, int ncb)
{
    __shared__ ushort sA[2][8192];            // 256 rows x 32 ushorts
    __shared__ ushort sBh[2][4096], sBl[2][4096];

    const int tid  = threadIdx.x;
    const int w    = tid >> 6, lane = tid & 63;
    const int m    = lane & 15, quad = lane >> 4;

    // bijective XCD swizzle (m204): orig -> wgid; chunks contiguous per XCD
    const int nwg = gridDim.x;
    const int orig = blockIdx.x;
    const int xcd = orig & 7, ii = orig >> 3;
    const int q = nwg >> 3, r = nwg & 7;
    const int wgid = (xcd < r ? xcd * (q + 1) : r * (q + 1) + (xcd - r) * q) + ii;
    const int row0 = (wgid / ncb) * 256;
    const int col0 = (wgid % ncb) * 128;
    const int wr   = (w >> 1) * 64;
    const int wc   = (w & 1) * 64;

    // staging: wave w covers A rows w*32..w*32+31 (2 issues) and B col
    // w*16+sub. lane -> (sub, kc); LDS unit u = row*4 + kc holds chunk
    // kc^((sub>>1)&3).
    const int sub = lane >> 2;
    const int kc  = lane & 3;
    const int kcs = kc ^ ((sub >> 1) & 3);
    const int arow0 = row0 + w * 32 + sub;
    const int arow1 = arow0 + 16;
    const int arow0c = arow0 < GN_N ? arow0 : 0;   // clamp: in-bounds DMA
    const int arow1c = arow1 < GN_N ? arow1 : 0;
    const ushort* aSrc0 = Aptr + (size_t)arow0c * lda + kcs * 8;
    const ushort* aSrc1 = Aptr + (size_t)arow1c * lda + kcs * 8;
    const ushort* bhSrc = Bh + (size_t)(col0 + w * 16 + sub) * K + kcs * 8;
    const ushort* blSrc = Bl + (size_t)(col0 + w * 16 + sub) * K + kcs * 8;

    floatx4 acc[4][4];
    #pragma unroll
    for (int i = 0; i < 4; ++i)
        #pragma unroll
        for (int j = 0; j < 4; ++j) acc[i][j] = (floatx4){0.f, 0.f, 0.f, 0.f};

    auto stage = [&](int buf, int k0) {
        __builtin_amdgcn_global_load_lds(
            (const __attribute__((address_space(1))) void*)(aSrc0 + k0),
            (__attribute__((address_space(3))) void*)&sA[buf][w * 1024], 16, 0, 0);
        __builtin_amdgcn_global_load_lds(
            (const __attribute__((address_space(1))) void*)(aSrc1 + k0),
            (__attribute__((address_space(3))) void*)&sA[buf][w * 1024 + 512], 16, 0, 0);
        __builtin_amdgcn_global_load_lds(
            (const __attribute__((address_space(1))) void*)(bhSrc + k0),
            (__attribute__((address_space(3))) void*)&sBh[buf][w * 512], 16, 0, 0);
        __builtin_amdgcn_global_load_lds(
            (const __attribute__((address_space(1))) void*)(blSrc + k0),
            (__attribute__((address_space(3))) void*)&sBl[buf][w * 512], 16, 0, 0);
    };

    const int nt = K >> 5;
    stage(0, 0);
    __syncthreads();

    const int rsw = (quad ^ ((m >> 1) & 3)) * 8;   // read-side swizzle (ushorts)
    int cur = 0;
    for (int t = 0; t < nt; ++t) {
        if (t + 1 < nt) stage(cur ^ 1, (t + 1) << 5);
        short8 bhf[4], blf[4];
        #pragma unroll
        for (int ct = 0; ct < 4; ++ct) {
            bhf[ct] = *(const short8*)&sBh[cur][(wc + ct * 16 + m) * 32 + rsw];
            blf[ct] = *(const short8*)&sBl[cur][(wc + ct * 16 + m) * 32 + rsw];
        }
        #pragma unroll
        for (int rt = 0; rt < 4; ++rt) {
            short8 ahf = *(const short8*)&sA[cur][(wr + rt * 16 + m) * 32 + rsw];
            #pragma unroll
            for (int ct = 0; ct < 4; ++ct) {
                acc[rt][ct] = __builtin_amdgcn_mfma_f32_16x16x32_bf16(ahf, bhf[ct], acc[rt][ct], 0, 0, 0);
                acc[rt][ct] = __builtin_amdgcn_mfma_f32_16x16x32_bf16(ahf, blf[ct], acc[rt][ct], 0, 0, 0);
            }
        }
        __syncthreads();
        cur ^= 1;
    }

    #pragma unroll
    for (int rt = 0; rt < 4; ++rt) {
        #pragma unroll
        for (int ct = 0; ct < 4; ++ct) {
            int ocol = col0 + wc + ct * 16 + m;
            float bb = bias[ocol];
            #pragma unroll
            for (int reg = 0; reg < 4; ++reg) {
                int orow = row0 + wr + rt * 16 + quad * 4 + reg;
                if (orow >= GN_N) continue;
                Obf[(size_t)orow * ldo + ocol] = f2bf_rne(acc[rt][ct][reg] + bb);
            }
        }
    }
}

// ---------------- CSR build ----------------
__global__ void zero_ds(int* __restrict__ deg, int* __restrict__ se)
{
    int i = blockIdx.x * 256 + threadIdx.x;
    if (i < GN_N) deg[i] = 0;
    else if (i < GN_N + 64) se[i - GN_N] = 0;
}

__global__ void hist_kernel(const int* __restrict__ dst, int* __restrict__ deg)
{
    int e = blockIdx.x * 256 + threadIdx.x;
    if (e < GN_E) atomicAdd(&deg[dst[e]], 1);
}

__global__ void scan1(const int* __restrict__ deg, int* __restrict__ rp, int* __restrict__ bsums)
{
    __shared__ int s[256];
    int b = blockIdx.x, t = threadIdx.x;
    int i = b * 256 + t;
    int v = (i < GN_N) ? deg[i] : 0;
    s[t] = v;
    __syncthreads();
    for (int off = 1; off < 256; off <<= 1) {
        int x = (t >= off) ? s[t - off] : 0;
        __syncthreads();
        s[t] += x;
        __syncthreads();
    }
    if (i < GN_N) rp[i] = s[t] - v;
    if (t == 255) bsums[b] = s[255];
}

__global__ __launch_bounds__(512) void scan2(int* bsums, int nb)
{
    __shared__ int s[512];
    int t = threadIdx.x;
    int v = (t < nb) ? bsums[t] : 0;
    s[t] = v;
    __syncthreads();
    for (int off = 1; off < 512; off <<= 1) {
        int x = (t >= off) ? s[t - off] : 0;
        __syncthreads();
        s[t] += x;
        __syncthreads();
    }
    if (t < nb) bsums[t] = s[t] - v;
}

__global__ void scan3(const int* __restrict__ bsums, int* __restrict__ rp, int* __restrict__ cursor)
{
    int b = blockIdx.x, t = threadIdx.x;
    int i = b * 256 + t;
    if (i < GN_N) {
        int v = rp[i] + bsums[b];
        rp[i] = v; cursor[i] = v;
    }
    if (i == 0) rp[GN_N] = GN_E;
}

__global__ void scatter_kernel(
    const int* __restrict__ src, const int* __restrict__ dst,
    int* __restrict__ cursor, int* __restrict__ elist)
{
    int e = blockIdx.x * 256 + threadIdx.x;
    if (e >= GN_E) return;
    int d = dst[e];
    int pos = atomicAdd(&cursor[d], 1);
    elist[pos] = src[e];
}

// Layer-1 gather. Gbf row 256 = [K64|QV128|S64]. 4 nodes/wave, 8-edge batch.
// Writes leaky(h1_pre) bf16 [N][64].
__global__ __launch_bounds__(256, 2) void edge_gather_w(
    const ushort* __restrict__ Gbf, ushort* __restrict__ Abf,
    const int* __restrict__ row_ptr, const int* __restrict__ elist)
{
    int w = threadIdx.x >> 6, c = threadIdx.x & 63;
    int n0 = blockIdx.x * 16 + w * 4;

    float k[4], acc[4];
    int beg[4], end[4];
    #pragma unroll
    for (int j = 0; j < 4; ++j) {
        int node = n0 + j;
        bool ok = node < GN_N;
        int nd = ok ? node : 0;
        beg[j] = row_ptr[nd];
        end[j] = ok ? row_ptr[nd + 1] : beg[j];
        k[j]   = bf2f(Gbf[(size_t)nd * 256 + c]);
        acc[j] = bf2f(Gbf[(size_t)nd * 256 + 192 + c]);
    }
    int s[32];
    #pragma unroll
    for (int j = 0; j < 4; ++j) {
        #pragma unroll
        for (int e = 0; e < 8; ++e) {
            int idx = beg[j] + e;
            s[j * 8 + e] = elist[idx < end[j] ? idx : 0];
        }
    }
    uint qv[32];
    #pragma unroll
    for (int je = 0; je < 32; ++je)
        qv[je] = *(const uint*)&Gbf[(size_t)s[je] * 256 + 64 + 2 * c];
    #pragma unroll
    for (int j = 0; j < 4; ++j) {
        #pragma unroll
        for (int e = 0; e < 8; ++e) {
            if (beg[j] + e < end[j]) {
                uint p = qv[j * 8 + e];
                float gt = k[j] + bf2f((ushort)(p & 0xffffu));
                if (gt > 0.f) acc[j] += gt * bf2f((ushort)(p >> 16));
            }
        }
    }
    #pragma unroll
    for (int j = 0; j < 4; ++j) {
        for (int i = beg[j] + 8; i < end[j]; ++i) {
            int ss = elist[i];
            uint p = *(const uint*)&Gbf[(size_t)ss * 256 + 64 + 2 * c];
            float gt = k[j] + bf2f((ushort)(p & 0xffffu));
            if (gt > 0.f) acc[j] += gt * bf2f((ushort)(p >> 16));
        }
    }
    #pragma unroll
    for (int j = 0; j < 4; ++j)
        if (n0 + j < GN_N) {
            float a = acc[j];
            a = a > 0.f ? a : 0.01f * a;   // leaky here (fp32) -> gemm is pure copy
            Abf[(size_t)(n0 + j) * 64 + c] = f2bf_rne(a);
        }
}

// Layer-2 dual gather. Gbf row 512 = [K128|QV256|S128]; thread handles
// channels c and 64+c. Writes leaky(h2_pre) bf16 [N][128].
__global__ __launch_bounds__(256, 2) void edge_gather_w2(
    const ushort* __restrict__ Gbf, ushort* __restrict__ Abf,
    const int* __restrict__ row_ptr, const int* __restrict__ elist)
{
    int w = threadIdx.x >> 6, c = threadIdx.x & 63;
    int n0 = blockIdx.x * 16 + w * 4;

    float k0[4], k1[4], a0[4], a1[4];
    int beg[4], end[4];
    #pragma unroll
    for (int j = 0; j < 4; ++j) {
        int node = n0 + j;
        bool ok = node < GN_N;
        int nd = ok ? node : 0;
        beg[j] = row_ptr[nd];
        end[j] = ok ? row_ptr[nd + 1] : beg[j];
        size_t b = (size_t)nd * 512;
        k0[j] = bf2f(Gbf[b + c]);
        k1[j] = bf2f(Gbf[b + 64 + c]);
        a0[j] = bf2f(Gbf[b + 384 + c]);
        a1[j] = bf2f(Gbf[b + 448 + c]);
    }
    int s[32];
    #pragma unroll
    for (int j = 0; j < 4; ++j) {
        #pragma unroll
        for (int e = 0; e < 8; ++e) {
            int idx = beg[j] + e;
            s[j * 8 + e] = elist[idx < end[j] ? idx : 0];
        }
    }
    uint qv0[32], qv1[32];
    #pragma unroll
    for (int je = 0; je < 32; ++je) {
        size_t b = (size_t)s[je] * 512;
        qv0[je] = *(const uint*)&Gbf[b + 128 + 2 * c];
        qv1[je] = *(const uint*)&Gbf[b + 256 + 2 * c];
    }
    #pragma unroll
    for (int j = 0; j < 4; ++j) {
        #pragma unroll
        for (int e = 0; e < 8; ++e) {
            if (beg[j] + e < end[j]) {
                uint p = qv0[j * 8 + e];
                float gt = k0[j] + bf2f((ushort)(p & 0xffffu));
                if (gt > 0.f) a0[j] += gt * bf2f((ushort)(p >> 16));
                uint q = qv1[j * 8 + e];
                float gu = k1[j] + bf2f((ushort)(q & 0xffffu));
                if (gu > 0.f) a1[j] += gu * bf2f((ushort)(q >> 16));
            }
        }
    }
    #pragma unroll
    for (int j = 0; j < 4; ++j) {
        for (int i = beg[j] + 8; i < end[j]; ++i) {
            size_t b = (size_t)elist[i] * 512;
            uint p = *(const uint*)&Gbf[b + 128 + 2 * c];
            uint q = *(const uint*)&Gbf[b + 256 + 2 * c];
            float gt = k0[j] + bf2f((ushort)(p & 0xffffu));
            if (gt > 0.f) a0[j] += gt * bf2f((ushort)(p >> 16));
            float gu = k1[j] + bf2f((ushort)(q & 0xffffu));
            if (gu > 0.f) a1[j] += gu * bf2f((ushort)(q >> 16));
        }
    }
    #pragma unroll
    for (int j = 0; j < 4; ++j)
        if (n0 + j < GN_N) {
            float x = a0[j], y = a1[j];
            x = x > 0.f ? x : 0.01f * x;
            y = y > 0.f ? y : 0.01f * y;
            Abf[(size_t)(n0 + j) * 128 + c]      = f2bf_rne(x);
            Abf[(size_t)(n0 + j) * 128 + 64 + c] = f2bf_rne(y);
        }
}

// Layer-3 dual gather + leaky + pool. Gbf row 512; channels c0+c, c0+64+c.
__global__ __launch_bounds__(256, 2) void edge_gather_pool2(
    const ushort* __restrict__ Gbf,
    const int* __restrict__ row_ptr, const int* __restrict__ elist,
    const int* __restrict__ batch,
    float* __restrict__ sums, int c0)
{
    __shared__ float red[16][128];
    __shared__ int gid[16];
    int w = threadIdx.x >> 6, c = threadIdx.x & 63;
    int n0 = blockIdx.x * 16 + w * 4;

    float k0[4], k1[4], a0[4], a1[4];
    int beg[4], end[4];
    #pragma unroll
    for (int j = 0; j < 4; ++j) {
        int node = n0 + j;
        bool ok = node < GN_N;
        int nd = ok ? node : 0;
        beg[j] = row_ptr[nd];
        end[j] = ok ? row_ptr[nd + 1] : beg[j];
        size_t b = (size_t)nd * 512;
        k0[j] = bf2f(Gbf[b + c]);
        k1[j] = bf2f(Gbf[b + 64 + c]);
        a0[j] = ok ? bf2f(Gbf[b + 384 + c]) : 0.f;
        a1[j] = ok ? bf2f(Gbf[b + 448 + c]) : 0.f;
    }
    int s[32];
    #pragma unroll
    for (int j = 0; j < 4; ++j) {
        #pragma unroll
        for (int e = 0; e < 8; ++e) {
            int idx = beg[j] + e;
            s[j * 8 + e] = elist[idx < end[j] ? idx : 0];
        }
    }
    uint qv0[32], qv1[32];
    #pragma unroll
    for (int je = 0; je < 32; ++je) {
        size_t b = (size_t)s[je] * 512;
        qv0[je] = *(const uint*)&Gbf[b + 128 + 2 * c];
        qv1[je] = *(const uint*)&Gbf[b + 256 + 2 * c];
    }
    #pragma unroll
    for (int j = 0; j < 4; ++j) {
        #pragma unroll
        for (int e = 0; e < 8; ++e) {
            if (beg[j] + e < end[j]) {
                uint p = qv0[j * 8 + e];
                float gt = k0[j] + bf2f((ushort)(p & 0xffffu));
                if (gt > 0.f) a0[j] += gt * bf2f((ushort)(p >> 16));
                uint q = qv1[j * 8 + e];
                float gu = k1[j] + bf2f((ushort)(q & 0xffffu));
                if (gu > 0.f) a1[j] += gu * bf2f((ushort)(q >> 16));
            }
        }
    }
    #pragma unroll
    for (int j = 0; j < 4; ++j) {
        for (int i = beg[j] + 8; i < end[j]; ++i) {
            size_t b = (size_t)elist[i] * 512;
            uint p = *(const uint*)&Gbf[b + 128 + 2 * c];
            uint q = *(const uint*)&Gbf[b + 256 + 2 * c];
            float gt = k0[j] + bf2f((ushort)(p & 0xffffu));
            if (gt > 0.f) a0[j] += gt * bf2f((ushort)(p >> 16));
            float gu = k1[j] + bf2f((ushort)(q & 0xffffu));
            if (gu > 0.f) a1[j] += gu * bf2f((ushort)(q >> 16));
        }
    }
    #pragma unroll
    for (int j = 0; j < 4; ++j) {
        float x = a0[j], y = a1[j];
        red[w * 4 + j][c]      = x > 0.f ? x : 0.01f * x;
        red[w * 4 + j][64 + c] = y > 0.f ? y : 0.01f * y;
    }
    if (c < 4) {
        int node = n0 + c;
        gid[w * 4 + c] = (node < GN_N) ? batch[node] : -1;
    }
    __syncthreads();
    if (w == 0) {
        int stripe = blockIdx.x & 31;
        int i = 0;
        while (i < 16) {
            int gg = gid[i];
            float s0 = 0.f, s1 = 0.f;
            int j = i;
            while (j < 16 && gid[j] == gg) { s0 += red[j][c]; s1 += red[j][64 + c]; ++j; }
            if (gg >= 0) {
                float* dstp = &sums[(size_t)(stripe * GN_G + gg) * 256 + c0 + c];
                atomicAdd(dstp, s0);
                atomicAdd(dstp + 64, s1);
            }
            i = j;
        }
    }
}

// One block per graph: reduce 32 stripes; Pl = sums[g]/cnt[g] (cnt from se);
// Pg = Pl @ Wl3 + bl3; BN-MLP chain.
__global__ __launch_bounds__(256) void mlp_kernel(
    const float* __restrict__ sums, const int* __restrict__ se,
    const float* __restrict__ Wl3, const float* __restrict__ bl3,
    const float* __restrict__ W1, const float* __restrict__ b1,
    const float* __restrict__ Wh, const float* __restrict__ bh,
    const float* __restrict__ Wo, const float* __restrict__ bo,
    const float* __restrict__ gamma, const float* __restrict__ beta,
    const float* __restrict__ mean, const float* __restrict__ var,
    float* __restrict__ out)
{
    __shared__ float sp[256];
    __shared__ float pg[256];
    __shared__ float h0[64], h1[64];
    const int g = blockIdx.x;
    const int t = threadIdx.x;
    const float cntg = (float)(se[32 + g] - se[g]);
    const float inv = 1.0f / fmaxf(cntg, 1.0f);

    {
        float acc = 0.f;
        #pragma unroll 8
        for (int st = 0; st < 32; ++st)
            acc += sums[(size_t)(st * GN_G + g) * 256 + t];
        sp[t] = acc * inv;
    }
    __syncthreads();

    {
        float a0 = 0.f, a1 = 0.f, a2 = 0.f, a3 = 0.f;
        #pragma unroll 4
        for (int k = 0; k < 256; k += 4) {
            a0 += sp[k + 0] * Wl3[(k + 0) * 256 + t];
            a1 += sp[k + 1] * Wl3[(k + 1) * 256 + t];
            a2 += sp[k + 2] * Wl3[(k + 2) * 256 + t];
            a3 += sp[k + 3] * Wl3[(k + 3) * 256 + t];
        }
        pg[t] = bl3[t] + ((a0 + a1) + (a2 + a3));
    }
    __syncthreads();

    if (t < 64) {
        float a0 = 0.f, a1 = 0.f, a2 = 0.f, a3 = 0.f;
        #pragma unroll 4
        for (int k = 0; k < 256; k += 4) {
            a0 += pg[k + 0] * W1[(k + 0) * 64 + t];
            a1 += pg[k + 1] * W1[(k + 1) * 64 + t];
            a2 += pg[k + 2] * W1[(k + 2) * 64 + t];
            a3 += pg[k + 3] * W1[(k + 3) * 64 + t];
        }
        float acc = b1[t] + ((a0 + a1) + (a2 + a3));
        float sc = gamma[t] * rsqrtf(var[t] + 1e-5f);
        acc = (acc - mean[t]) * sc + beta[t];
        h0[t] = fmaxf(acc, 0.0f);
    }
    __syncthreads();

    for (int L = 0; L < 3; ++L) {
        const float* W  = Wh + L * 64 * 64;
        const float* hin  = (L & 1) ? h1 : h0;
        float*       hout = (L & 1) ? h0 : h1;
        if (t < 64) {
            const float* ga = gamma + (L + 1) * 64;
            const float* be = beta  + (L + 1) * 64;
            const float* me = mean  + (L + 1) * 64;
            const float* va = var   + (L + 1) * 64;
            float a0 = 0.f, a1 = 0.f, a2 = 0.f, a3 = 0.f;
            #pragma unroll 4
            for (int k = 0; k < 64; k += 4) {
                a0 += hin[k + 0] * W[(k + 0) * 64 + t];
                a1 += hin[k + 1] * W[(k + 1) * 64 + t];
                a2 += hin[k + 2] * W[(k + 2) * 64 + t];
                a3 += hin[k + 3] * W[(k + 3) * 64 + t];
            }
            float acc = (bh + L * 64)[t] + ((a0 + a1) + (a2 + a3));
            float sc = ga[t] * rsqrtf(va[t] + 1e-5f);
            acc = (acc - me[t]) * sc + be[t];
            hout[t] = fmaxf(acc, 0.0f);
        }
        __syncthreads();
    }

    if (t < 8) {
        const float* hf = h1;
        float acc = bo[t];
        for (int k = 0; k < 64; ++k) acc += hf[k] * Wo[k * 8 + t];
        out[g * 8 + t] = acc;
    }
}

extern "C" void kernel_launch(void* const* d_in, const int* in_sizes, int n_in,
                              void* d_out, int out_size, void* d_ws, size_t ws_size,
                              hipStream_t stream)
{
    const int N = GN_N, E = GN_E;
    const int*   edge_index = (const int*)d_in[1];
    const int*   batch      = (const int*)d_in[2];
    const int*   src = edge_index;
    const int*   dst = edge_index + E;
    auto F = [&](int i) { return (const float*)d_in[i]; };

    // ---- workspace layout ----
    float* ws    = (float*)d_ws;
    float* sums  = ws;                          // 32 stripes x 32 x 256
    float* bcat  = sums + 32 * GN_G * 256;      // 1792
    ushort* Whi  = (ushort*)(bcat + 1792);
    ushort* Wlo  = Whi + W_TOTAL;
    ushort* xbf  = Wlo + W_TOTAL;               // N x 128 bf16
    ushort* h1bf = xbf + (size_t)N * 128;       // N x 64 bf16 (leaky'd)
    ushort* h2bf = h1bf + (size_t)N * 64;       // N x 128 bf16 (leaky'd)
    ushort* Gbf  = h2bf + (size_t)N * 128;      // N x 512 bf16
    int* deg     = (int*)(Gbf + (size_t)N * 512);
    int* cursor  = deg + N;
    int* row_ptr = cursor + N;                  // N+1
    int* elist   = row_ptr + (N + 1);           // E
    int* bsums   = elist + E;                   // 512
    int* se      = bsums + 512;                 // 64

    size_t need = (size_t)((char*)(se + 64) - (char*)ws);
    if (ws_size < need) return;

    // ---- CSR build ----
    const int eb = (E + 255) / 256;
    const int nb = (N + 255) / 256;
    zero_ds<<<(N + 64 + 255) / 256, 256, 0, stream>>>(deg, se);
    hist_kernel<<<eb, 256, 0, stream>>>(dst, deg);
    scan1<<<nb, 256, 0, stream>>>(deg, row_ptr, bsums);
    scan2<<<1, 512, 0, stream>>>(bsums, nb);
    scan3<<<nb, 256, 0, stream>>>(bsums, row_ptr, cursor);
    scatter_kernel<<<eb, 256, 0, stream>>>(src, dst, cursor, elist);

    // ---- fused prep: packs + composes + zero sums + x->bf16 + bounds ----
    PrepAll P;
    for (int g = 0; g < 4; ++g) { P.W1g[g] = F(3 + g);  P.b1g[g] = F(7 + g); }
    P.Wl1 = F(11); P.bl1 = F(12);
    for (int g = 0; g < 4; ++g) { P.W2g[g] = F(13 + g); P.b2g[g] = F(17 + g); }
    P.Wl2 = F(21); P.bl2 = F(22);
    for (int g = 0; g < 4; ++g) { P.W3g[g] = F(23 + g); P.b3g[g] = F(27 + g); }
    P.x = F(0);
    P.batch = batch;
    prep<<<(PREP_BD + 255) / 256, 256, 0, stream>>>(P, Whi, Wlo, bcat, xbf, sums, se);

    const int rb = (N + 255) / 256;
    const int gatherBlocks = (N + 15) / 16;

    // ---- layer 1 (256 cols: [K64|QV128|S64]) ----
    gemm2<<<2 * rb, 512, 0, stream>>>(
        xbf, 128, Whi, Wlo, bcat, Gbf, 256, 128, 2);
    edge_gather_w<<<gatherBlocks, 256, 0, stream>>>(Gbf, h1bf, row_ptr, elist);

    // ---- layer 2 (composed: leaky'd h1 @ Wl1Wg2; 512 cols, K=64) ----
    gemm2<<<4 * rb, 512, 0, stream>>>(
        h1bf, 64, Whi + WOFF_L2, Wlo + WOFF_L2, bcat + 256, Gbf, 512, 64, 4);
    edge_gather_w2<<<gatherBlocks, 256, 0, stream>>>(Gbf, h2bf, row_ptr, elist);

    // ---- layer 3 (composed: leaky'd h2 @ Wl2Wg3; 2 groups x 512, K=128) ----
    for (int ch = 0; ch < 2; ++ch) {
        size_t go = WOFF_L3 + (size_t)ch * 65536;
        gemm2<<<4 * rb, 512, 0, stream>>>(
            h2bf, 128, Whi + go, Wlo + go, bcat + 768 + ch * 512, Gbf, 512, 128, 4);
        edge_gather_pool2<<<gatherBlocks, 256, 0, stream>>>(
            Gbf, row_ptr, elist, batch, sums, ch * 128);
    }

    mlp_kernel<<<GN_G, 256, 0, stream>>>(sums, se, F(31), F(32),
                                         F(33), F(34), F(35), F(36), F(37), F(38),
                                         F(39), F(40), F(41), F(42),
                                         (float*)d_out);
}